// Round 1
// baseline (245.263 us; speedup 1.0000x reference)
//
#include <hip/hip_runtime.h>
#include <math.h>

#define Bn 8192
#define Dd 64
#define NAa 64
#define RK 32
#define Hh 16
#define Ee 128

__device__ __forceinline__ float fast_tanh(float x) {
    x = fminf(fmaxf(x, -15.f), 15.f);
    float e = __expf(2.f * x);
    return (e - 1.f) / (e + 1.f);
}

// Phase 1: per-batch low-rank attention -> R[b][c], c = h*64 + n  (1024 floats per b)
// MODE 0: write R to workspace (float[8192][1024])
// MODE 1: scatter-accumulate Rupper + Rupper^T into d_out via atomicAdd (out must be zeroed)
template <int MODE>
__global__ __launch_bounds__(256, 4)
void att_k1(const float* __restrict__ x, const float* __restrict__ L,
            const float* __restrict__ Aq, const float* __restrict__ Ak,
            const float* __restrict__ Av, const float* __restrict__ Ao,
            float* __restrict__ out) {
    const int b    = blockIdx.x;
    const int t    = threadIdx.x;
    const int lane = t & 63;
    const int w    = t >> 6;                       // wave id 0..3
    const int wu   = __builtin_amdgcn_readfirstlane(w);

    __shared__ float sQ[RK][68];   // +4 pad: row = 272B, 16B-aligned, bank-rotated
    __shared__ float sK[RK][68];
    __shared__ float sV[RK][68];
    __shared__ float sO[RK][68];
    __shared__ float sNum;

    // ---- load x column n=lane into registers (coalesced per-d dword loads) ----
    float xr[Dd];
    const float* xb = x + (size_t)b * (Dd * NAa);
#pragma unroll
    for (int d = 0; d < Dd; ++d) xr[d] = xb[d * NAa + lane];

    // ---- numN = count(L[b,0,:] >= 1) + 1 ----
    if (t < 64) {
        float lv = L[(size_t)b * NAa + t];
        unsigned long long m = __ballot(lv >= 1.0f);
        if (t == 0) sNum = (float)__popcll(m) + 1.0f;
    }

    // ---- Q,K,V = tanh(A @ x[b]) ; thread owns column n, rows r = wu + 4k ----
    {
        const float* Am[3] = {Aq, Ak, Av};
        float(*const sMat[3])[68] = {sQ, sK, sV};
#pragma unroll
        for (int m = 0; m < 3; ++m) {
            const float* Abase = Am[m];
#pragma unroll
            for (int k = 0; k < 8; ++k) {
                const int r = wu + 4 * k;
                const float* Ar = Abase + r * Dd;   // wave-uniform -> scalar loads
                float acc = 0.f;
#pragma unroll
                for (int d = 0; d < Dd; ++d) acc = fmaf(Ar[d], xr[d], acc);
                sMat[m][r][lane] = fast_tanh(acc);
            }
        }
    }
    __syncthreads();

    // ---- scores[r][s] = (Q[r]·K[s]) * rsqrt(numN); softmax over s ----
    // thread: s = lane&31, half = lane>>5 handles n-range [half*32, half*32+32)
    const int s    = lane & 31;
    const int half = lane >> 5;
    const float inv = rsqrtf(sNum);

    float kreg[32];
#pragma unroll
    for (int c = 0; c < 8; ++c) {
        float4 kv = *(const float4*)&sK[s][half * 32 + 4 * c];
        kreg[4 * c]     = kv.x;
        kreg[4 * c + 1] = kv.y;
        kreg[4 * c + 2] = kv.z;
        kreg[4 * c + 3] = kv.w;
    }

    float p[8];
#pragma unroll
    for (int kk = 0; kk < 8; ++kk) {
        const int r = wu + 4 * kk;
        float sc = 0.f;
#pragma unroll
        for (int c = 0; c < 8; ++c) {
            float4 qv = *(const float4*)&sQ[r][half * 32 + 4 * c];
            sc = fmaf(qv.x, kreg[4 * c], sc);
            sc = fmaf(qv.y, kreg[4 * c + 1], sc);
            sc = fmaf(qv.z, kreg[4 * c + 2], sc);
            sc = fmaf(qv.w, kreg[4 * c + 3], sc);
        }
        sc += __shfl_xor(sc, 32);                 // combine the two n-halves
        p[kk] = sc * inv;
    }
#pragma unroll
    for (int kk = 0; kk < 8; ++kk) {
        float m = p[kk];
#pragma unroll
        for (int off = 16; off >= 1; off >>= 1) m = fmaxf(m, __shfl_xor(m, off));
        float e = __expf(p[kk] - m);
        float dsum = e;
#pragma unroll
        for (int off = 16; off >= 1; off >>= 1) dsum += __shfl_xor(dsum, off);
        p[kk] = e / dsum;                          // attn[r = wu+4kk][s], replicated in both halves
    }

    // ---- o[r][n] = sum_s attn[r][s] * V[s][n] ; attn rebroadcast via readlane ----
    float oacc[8];
#pragma unroll
    for (int k = 0; k < 8; ++k) oacc[k] = 0.f;
#pragma unroll
    for (int si = 0; si < 32; ++si) {
        float vv = sV[si][lane];
#pragma unroll
        for (int k = 0; k < 8; ++k)
            oacc[k] = fmaf(__shfl(p[k], si), vv, oacc[k]);
    }
#pragma unroll
    for (int k = 0; k < 8; ++k) sO[wu + 4 * k][lane] = oacc[k];
    __syncthreads();

    // ---- Rh[h][n] = tanh(Ao[h]·o[:,n]) ; R = Rh^2 ----
#pragma unroll
    for (int k = 0; k < 4; ++k) {
        const int h = wu + 4 * k;
        const float* AoR = Ao + h * RK;            // wave-uniform -> scalar loads
        float acc = 0.f;
#pragma unroll
        for (int r = 0; r < RK; ++r) acc = fmaf(AoR[r], sO[r][lane], acc);
        float rh  = fast_tanh(acc);
        float val = rh * rh;
        if (MODE == 0) {
            out[(size_t)b * 1024 + h * 64 + lane] = val;
        } else {
            const int e  = b >> 6;
            const int i  = b & 63;
            const int c  = h * 64 + lane;
            const int j  = c >> 4;
            const int k4 = c & 15;
            const int hr = (k4 >> 3) & 1, hc = (k4 >> 2) & 1;
            const int pr = (k4 >> 1) & 1, pc = k4 & 1;
            const int row = hr * 128 + 2 * i + pr;
            const int col = hc * 128 + 2 * j + pc;
            float* oe = out + (size_t)e * 65536;
            atomicAdd(&oe[row * 256 + col], val);
            atomicAdd(&oe[col * 256 + row], val);
        }
    }
}

// Phase 2 (ws path): assemble Rsym and graph-Laplacian transform.
// grid = 128 envs * 8 row-groups; block handles 32 rows x 256 cols.
__global__ __launch_bounds__(256)
void att_k2(const float* __restrict__ R, float* __restrict__ out) {
    const int e  = blockIdx.x >> 3;
    const int rg = blockIdx.x & 7;
    const int t  = threadIdx.x;
    const float* Re = R + (size_t)e * 65536;
    float* Oe       = out + (size_t)e * 65536;

    const int col = t;
    const int hc = col >> 7, j = (col >> 1) & 63, pc = col & 1;

    __shared__ float red[32][4];
    float rsv[32];

#pragma unroll
    for (int rr = 0; rr < 32; ++rr) {
        const int row = rg * 32 + rr;
        const int hr = row >> 7, i = (row >> 1) & 63, pr = row & 1;
        float t1 = Re[i * 1024 + j * 16 + hr * 8 + hc * 4 + pr * 2 + pc];
        float t2 = Re[j * 1024 + i * 16 + hc * 8 + hr * 4 + pc * 2 + pr];
        float rs = t1 + t2;
        rsv[rr] = rs;
        float sum = rs;
#pragma unroll
        for (int off = 32; off >= 1; off >>= 1) sum += __shfl_xor(sum, off);
        if ((t & 63) == 0) red[rr][t >> 6] = sum;
    }
    __syncthreads();
#pragma unroll
    for (int rr = 0; rr < 32; ++rr) {
        const int row = rg * 32 + rr;
        float tot = red[rr][0] + red[rr][1] + red[rr][2] + red[rr][3];
        Oe[row * 256 + col] = (col == row) ? tot : -rsv[rr];
    }
}

// Phase 3 (atomic fallback path): in-place Laplacian per row. grid = 128*256 rows.
__global__ __launch_bounds__(256)
void att_k3(float* __restrict__ out) {
    const size_t rowbase = (size_t)blockIdx.x * 256;
    const int t = threadIdx.x;
    float v = out[rowbase + t];
    float sum = v;
#pragma unroll
    for (int off = 32; off >= 1; off >>= 1) sum += __shfl_xor(sum, off);
    __shared__ float red[4];
    if ((t & 63) == 0) red[t >> 6] = sum;
    __syncthreads();
    float tot = red[0] + red[1] + red[2] + red[3];
    const int row = blockIdx.x & 255;
    out[rowbase + t] = (t == row) ? tot : -v;
}

extern "C" void kernel_launch(void* const* d_in, const int* in_sizes, int n_in,
                              void* d_out, int out_size, void* d_ws, size_t ws_size,
                              hipStream_t stream) {
    const float* x  = (const float*)d_in[0];
    const float* L  = (const float*)d_in[1];
    const float* Aq = (const float*)d_in[2];
    const float* Ak = (const float*)d_in[3];
    const float* Av = (const float*)d_in[4];
    const float* Ao = (const float*)d_in[5];
    float* out = (float*)d_out;

    const size_t need = (size_t)Bn * 1024 * sizeof(float);
    if (ws_size >= need) {
        float* R = (float*)d_ws;
        att_k1<0><<<Bn, 256, 0, stream>>>(x, L, Aq, Ak, Av, Ao, R);
        att_k2<<<Ee * 8, 256, 0, stream>>>(R, out);
    } else {
        hipMemsetAsync(d_out, 0, (size_t)out_size * sizeof(float), stream);
        att_k1<1><<<Bn, 256, 0, stream>>>(x, L, Aq, Ak, Av, Ao, out);
        att_k3<<<Ee * 256, 256, 0, stream>>>(out);
    }
}

// Round 2
// 203.642 us; speedup vs baseline: 1.2044x; 1.2044x over previous
//
#include <hip/hip_runtime.h>
#include <math.h>

#define Bn 8192
#define Dd 64
#define NAa 64
#define RK 32
#define Hh 16
#define Ee 128

__device__ __forceinline__ float fast_tanh(float x) {
    x = fminf(fmaxf(x, -15.f), 15.f);
    float e = __expf(2.f * x);
    return (e - 1.f) / (e + 1.f);
}

// Phase 1: per-batch low-rank attention -> R[b][c], c = h*64 + n  (1024 floats per b)
// MODE 0: write R to workspace (float[8192][1024])
// MODE 1: scatter-accumulate Rupper + Rupper^T into d_out via atomicAdd (out zeroed)
template <int MODE>
__global__ __launch_bounds__(256, 4)
void att_k1(const float* __restrict__ x, const float* __restrict__ L,
            const float* __restrict__ Aq, const float* __restrict__ Ak,
            const float* __restrict__ Av, const float* __restrict__ Ao,
            float* __restrict__ out) {
    const int b    = blockIdx.x;
    const int t    = threadIdx.x;
    const int lane = t & 63;
    const int w    = t >> 6;                       // wave id 0..3
    const int wu   = __builtin_amdgcn_readfirstlane(w);

    // sQ reused as attn-matrix storage in PV phase; sK reused as sO in Rh phase.
    __shared__ float sQ[RK][68];   // row = 272B, 16B-aligned for b128 reads
    __shared__ float sK[RK][68];
    __shared__ float sV[RK][68];
    __shared__ float sNum;

    const float* xb = x + (size_t)b * (Dd * NAa);

    // ---- numN = count(L[b,0,:] >= 1) + 1 ----
    if (t < 64) {
        float lv = L[(size_t)b * NAa + t];
        unsigned long long m = __ballot(lv >= 1.0f);
        if (t == 0) sNum = (float)__popcll(m) + 1.0f;
    }

    // ---- Q,K,V = tanh(A @ x[b]) ----
    // Thread owns column n = lane. d-loop split in two 32-chunks held in VGPRs;
    // all 24 accumulators (3 mats x 8 rows) live across the chunk -> x loaded once.
    float acc[3][8];
#pragma unroll
    for (int m = 0; m < 3; ++m)
#pragma unroll
        for (int k = 0; k < 8; ++k) acc[m][k] = 0.f;

    const float* Am[3] = {Aq, Ak, Av};
#pragma unroll
    for (int hf = 0; hf < 2; ++hf) {
        float xv[32];
#pragma unroll
        for (int d = 0; d < 32; ++d) xv[d] = xb[(hf * 32 + d) * NAa + lane];
#pragma unroll
        for (int m = 0; m < 3; ++m) {
#pragma unroll
            for (int k = 0; k < 8; ++k) {
                const float* Ar = Am[m] + (wu + 4 * k) * Dd + hf * 32; // wave-uniform -> s_load
                float a = acc[m][k];
#pragma unroll
                for (int d = 0; d < 32; ++d) a = fmaf(Ar[d], xv[d], a);
                acc[m][k] = a;
            }
        }
    }
    float(*const sMat[3])[68] = {sQ, sK, sV};
#pragma unroll
    for (int m = 0; m < 3; ++m)
#pragma unroll
        for (int k = 0; k < 8; ++k)
            sMat[m][wu + 4 * k][lane] = fast_tanh(acc[m][k]);
    __syncthreads();

    // ---- scores[r][s] = (Q[r]·K[s]) * rsqrt(numN) ----
    // thread: s = lane&31, half = lane>>5 computes partial over n in [half*32, half*32+32)
    const int s    = lane & 31;
    const int half = lane >> 5;
    const float inv = rsqrtf(sNum);

    float kreg[32];
#pragma unroll
    for (int c = 0; c < 8; ++c) {
        float4 kv = *(const float4*)&sK[s][half * 32 + 4 * c];
        kreg[4 * c]     = kv.x;
        kreg[4 * c + 1] = kv.y;
        kreg[4 * c + 2] = kv.z;
        kreg[4 * c + 3] = kv.w;
    }

    float sc8[8];
#pragma unroll
    for (int kk = 0; kk < 8; ++kk) {
        const int r = wu + 4 * kk;
        float sc = 0.f;
#pragma unroll
        for (int c = 0; c < 8; ++c) {
            float4 qv = *(const float4*)&sQ[r][half * 32 + 4 * c];
            sc = fmaf(qv.x, kreg[4 * c], sc);
            sc = fmaf(qv.y, kreg[4 * c + 1], sc);
            sc = fmaf(qv.z, kreg[4 * c + 2], sc);
            sc = fmaf(qv.w, kreg[4 * c + 3], sc);
        }
        sc += __shfl_xor(sc, 32);                 // combine the two n-halves
        sc8[kk] = sc * inv;
    }

    // ---- softmax: each half owns 4 rows (kk = 2q + half) -> half the swizzles ----
    float pown[4];
#pragma unroll
    for (int q = 0; q < 4; ++q)
        pown[q] = half ? sc8[2 * q + 1] : sc8[2 * q];   // static indices + cndmask
#pragma unroll
    for (int q = 0; q < 4; ++q) {
        float m = pown[q];
#pragma unroll
        for (int off = 16; off >= 1; off >>= 1) m = fmaxf(m, __shfl_xor(m, off));
        float e = __expf(pown[q] - m);
        float dsum = e;
#pragma unroll
        for (int off = 16; off >= 1; off >>= 1) dsum += __shfl_xor(dsum, off);
        pown[q] = e / dsum;                        // attn[wu + 8q + 4*half][s]
    }

    __syncthreads();   // all sQ/sK reads done before attn overwrites sQ
#pragma unroll
    for (int q = 0; q < 4; ++q)
        sQ[wu + 8 * q + 4 * half][s] = pown[q];
    __syncthreads();

    // ---- o[r][n] = sum_s attn[r][s] * V[s][n] ----
    // attn rows via wave-uniform ds_read_b128 (broadcast); V column per lane.
    float oacc[8];
#pragma unroll
    for (int k = 0; k < 8; ++k) oacc[k] = 0.f;
#pragma unroll
    for (int sb = 0; sb < 8; ++sb) {
        float4 arow[8];
#pragma unroll
        for (int kk = 0; kk < 8; ++kk)
            arow[kk] = *(const float4*)&sQ[wu + 4 * kk][4 * sb];
#pragma unroll
        for (int ds = 0; ds < 4; ++ds) {
            float vv = sV[4 * sb + ds][lane];
#pragma unroll
            for (int kk = 0; kk < 8; ++kk) {
                float a = (ds == 0) ? arow[kk].x : (ds == 1) ? arow[kk].y
                        : (ds == 2) ? arow[kk].z : arow[kk].w;
                oacc[kk] = fmaf(a, vv, oacc[kk]);
            }
        }
    }
#pragma unroll
    for (int k = 0; k < 8; ++k) sK[wu + 4 * k][lane] = oacc[k];  // sO := sK region
    __syncthreads();

    // ---- Rh[h][n] = tanh(Ao[h]·o[:,n]) ; R = Rh^2 ----
    float col[32];
#pragma unroll
    for (int r = 0; r < 32; ++r) col[r] = sK[r][lane];
#pragma unroll
    for (int k = 0; k < 4; ++k) {
        const int h = wu + 4 * k;
        const float* AoR = Ao + h * RK;            // wave-uniform -> s_load
        float a2 = 0.f;
#pragma unroll
        for (int r = 0; r < RK; ++r) a2 = fmaf(AoR[r], col[r], a2);
        float rh  = fast_tanh(a2);
        float val = rh * rh;
        if (MODE == 0) {
            out[(size_t)b * 1024 + h * 64 + lane] = val;
        } else {
            const int e  = b >> 6;
            const int i  = b & 63;
            const int c  = h * 64 + lane;
            const int j  = c >> 4;
            const int k4 = c & 15;
            const int hr = (k4 >> 3) & 1, hc = (k4 >> 2) & 1;
            const int pr = (k4 >> 1) & 1, pc = k4 & 1;
            const int row = hr * 128 + 2 * i + pr;
            const int colo = hc * 128 + 2 * j + pc;
            float* oe = out + (size_t)e * 65536;
            atomicAdd(&oe[row * 256 + colo], val);
            atomicAdd(&oe[colo * 256 + row], val);
        }
    }
}

// Phase 2 (ws path): assemble Rsym and graph-Laplacian transform.
// grid = 128 envs * 8 row-groups; block handles 32 rows x 256 cols.
__global__ __launch_bounds__(256)
void att_k2(const float* __restrict__ R, float* __restrict__ out) {
    const int e  = blockIdx.x >> 3;
    const int rg = blockIdx.x & 7;
    const int t  = threadIdx.x;
    const float* Re = R + (size_t)e * 65536;
    float* Oe       = out + (size_t)e * 65536;

    const int col = t;
    const int hc = col >> 7, j = (col >> 1) & 63, pc = col & 1;

    __shared__ float red[32][4];
    float rsv[32];

#pragma unroll
    for (int rr = 0; rr < 32; ++rr) {
        const int row = rg * 32 + rr;
        const int hr = row >> 7, i = (row >> 1) & 63, pr = row & 1;
        float t1 = Re[i * 1024 + j * 16 + hr * 8 + hc * 4 + pr * 2 + pc];
        float t2 = Re[j * 1024 + i * 16 + hc * 8 + hr * 4 + pc * 2 + pr];
        float rs = t1 + t2;
        rsv[rr] = rs;
        float sum = rs;
#pragma unroll
        for (int off = 32; off >= 1; off >>= 1) sum += __shfl_xor(sum, off);
        if ((t & 63) == 0) red[rr][t >> 6] = sum;
    }
    __syncthreads();
#pragma unroll
    for (int rr = 0; rr < 32; ++rr) {
        const int row = rg * 32 + rr;
        float tot = red[rr][0] + red[rr][1] + red[rr][2] + red[rr][3];
        Oe[row * 256 + col] = (col == row) ? tot : -rsv[rr];
    }
}

// Phase 3 (atomic fallback path): in-place Laplacian per row. grid = 128*256 rows.
__global__ __launch_bounds__(256)
void att_k3(float* __restrict__ out) {
    const size_t rowbase = (size_t)blockIdx.x * 256;
    const int t = threadIdx.x;
    float v = out[rowbase + t];
    float sum = v;
#pragma unroll
    for (int off = 32; off >= 1; off >>= 1) sum += __shfl_xor(sum, off);
    __shared__ float red[4];
    if ((t & 63) == 0) red[t >> 6] = sum;
    __syncthreads();
    float tot = red[0] + red[1] + red[2] + red[3];
    const int row = blockIdx.x & 255;
    out[rowbase + t] = (t == row) ? tot : -v;
}

extern "C" void kernel_launch(void* const* d_in, const int* in_sizes, int n_in,
                              void* d_out, int out_size, void* d_ws, size_t ws_size,
                              hipStream_t stream) {
    const float* x  = (const float*)d_in[0];
    const float* L  = (const float*)d_in[1];
    const float* Aq = (const float*)d_in[2];
    const float* Ak = (const float*)d_in[3];
    const float* Av = (const float*)d_in[4];
    const float* Ao = (const float*)d_in[5];
    float* out = (float*)d_out;

    const size_t need = (size_t)Bn * 1024 * sizeof(float);
    if (ws_size >= need) {
        float* R = (float*)d_ws;
        att_k1<0><<<Bn, 256, 0, stream>>>(x, L, Aq, Ak, Av, Ao, R);
        att_k2<<<Ee * 8, 256, 0, stream>>>(R, out);
    } else {
        hipMemsetAsync(d_out, 0, (size_t)out_size * sizeof(float), stream);
        att_k1<1><<<Bn, 256, 0, stream>>>(x, L, Aq, Ak, Av, Ao, out);
        att_k3<<<Ee * 256, 256, 0, stream>>>(out);
    }
}

// Round 4
// 96.699 us; speedup vs baseline: 2.5364x; 2.1059x over previous
//
#include <hip/hip_runtime.h>
#include <math.h>

#define Bn 8192
#define Ee 128

typedef __attribute__((ext_vector_type(8))) short short8;   // 8 bf16 (4 VGPR) MFMA A/B frag
typedef __attribute__((ext_vector_type(4))) float f32x4;    // MFMA C/D frag

__device__ __forceinline__ float fast_tanh(float x) {
    x = fminf(fmaxf(x, -15.f), 15.f);
    float e = __expf(2.f * x);
    return (e - 1.f) / (e + 1.f);
}

// round-to-nearest-ish f32->bf16 (round-half-up in magnitude): plenty for 7.64 budget
__device__ __forceinline__ unsigned int bf1(float a) {
    return (__builtin_bit_cast(unsigned int, a) + 0x8000u) >> 16;
}
__device__ __forceinline__ unsigned int pack2bf(float a, float b) {
    unsigned int ua = (__builtin_bit_cast(unsigned int, a) + 0x8000u) >> 16;
    unsigned int ub = (__builtin_bit_cast(unsigned int, b) + 0x8000u) & 0xffff0000u;
    return ua | ub;
}

// ============================ MFMA main kernel ============================
// One block per batch element b. 4 waves. All GEMMs on 16x16x32 bf16 MFMA.
// Frag layouts (gfx950): A: row=lane&15, k=(lane>>4)*8+j (k-contig -> b128 from
// row-major LDS). B: col=lane&15, k=(lane>>4)*8+j (reads B-source's [col][k]
// row-major). C/D: col=lane&15, row=(lane>>4)*4+reg (verified m89/m91).
__global__ __launch_bounds__(256, 4)
void att_m1(const float* __restrict__ x, const float* __restrict__ L,
            const float* __restrict__ Aq, const float* __restrict__ Ak,
            const float* __restrict__ Av, const float* __restrict__ Ao,
            float* __restrict__ R) {
    const int b    = blockIdx.x;
    const int t    = threadIdx.x;
    const int lane = t & 63;
    const int w    = t >> 6;        // wave 0..3
    const int q    = lane >> 4;     // quarter 0..3
    const int m    = lane & 15;

    // strides (in shorts): 72 -> 144B rows (16B-aligned, 2-way bank spread)
    //                      40 ->  80B rows (16B-aligned)
    __shared__ __align__(16) short sA[3][32 * 72];   // Aq/Ak/Av bf16 [r][d]
    __shared__ __align__(16) short sAo[16 * 40];     // Ao bf16 [h][r]
    __shared__ __align__(16) short sQ[32 * 72];      // Q bf16 [r][n]
    __shared__ __align__(16) short sK[32 * 72];      // K bf16 [s][n]
    __shared__ __align__(16) short sVt[64 * 40];     // V^T bf16 [n][s]
    __shared__ __align__(16) short sP[32 * 40];      // attn bf16 [r][s]
    __shared__ __align__(16) float uni[1320];        // union: sS f32[32][33] | ot bf16[64][40]
    __shared__ float sNum;

    // ---- issue x column loads early (A-frags for QKV): lane needs
    // x[d = kc*32 + q*8 + j][n = w*16 + m], 16 dwords, 64B-coalesced per quarter ----
    float xf[16];
    {
        const float* p0 = x + (size_t)b * 4096 + (q * 8) * 64 + (w * 16 + m);
#pragma unroll
        for (int j = 0; j < 8; ++j) xf[j] = p0[j * 64];
        const float* p1 = p0 + 32 * 64;
#pragma unroll
        for (int j = 0; j < 8; ++j) xf[8 + j] = p1[j * 64];
    }

    // ---- numN = count(L[b,0,:] >= 1) + 1 ----
    if (t < 64) {
        float lv = L[(size_t)b * 64 + t];
        unsigned long long mk = __ballot(lv >= 1.0f);
        if (t == 0) sNum = (float)__popcll(mk) + 1.0f;
    }

    // ---- stage Aq/Ak/Av/Ao as bf16 into LDS ----
    {
        const float* Am[3] = {Aq, Ak, Av};
        const int r = t >> 3, dg = t & 7;
#pragma unroll
        for (int mat = 0; mat < 3; ++mat) {
            float4 v0 = *(const float4*)(Am[mat] + r * 64 + dg * 8);
            float4 v1 = *(const float4*)(Am[mat] + r * 64 + dg * 8 + 4);
            uint4 pk = {pack2bf(v0.x, v0.y), pack2bf(v0.z, v0.w),
                        pack2bf(v1.x, v1.y), pack2bf(v1.z, v1.w)};
            *(uint4*)&sA[mat][r * 72 + dg * 8] = pk;
        }
        if (t < 64) {
            const int rr = t >> 2, dg2 = t & 3;
            float4 v0 = *(const float4*)(Ao + rr * 32 + dg2 * 8);
            float4 v1 = *(const float4*)(Ao + rr * 32 + dg2 * 8 + 4);
            uint4 pk = {pack2bf(v0.x, v0.y), pack2bf(v0.z, v0.w),
                        pack2bf(v1.x, v1.y), pack2bf(v1.z, v1.w)};
            *(uint4*)&sAo[rr * 40 + dg2 * 8] = pk;
        }
    }
    __syncthreads();

    // ---- QKV (transposed GEMM): D[n][r] = sum_d x[d][n] * Am[r][d] ----
    // wave w owns n-tile w. A-frag from xf (global); B-frag = sA rows (k-contig).
    short8 afr[2];
    {
        uint4 pk0 = {pack2bf(xf[0], xf[1]), pack2bf(xf[2], xf[3]),
                     pack2bf(xf[4], xf[5]), pack2bf(xf[6], xf[7])};
        uint4 pk1 = {pack2bf(xf[8], xf[9]), pack2bf(xf[10], xf[11]),
                     pack2bf(xf[12], xf[13]), pack2bf(xf[14], xf[15])};
        afr[0] = __builtin_bit_cast(short8, pk0);
        afr[1] = __builtin_bit_cast(short8, pk1);
    }
#pragma unroll
    for (int mat = 0; mat < 3; ++mat) {
#pragma unroll
        for (int rt = 0; rt < 2; ++rt) {
            short8 bfr0 = *(const short8*)&sA[mat][(rt * 16 + m) * 72 + q * 8];
            short8 bfr1 = *(const short8*)&sA[mat][(rt * 16 + m) * 72 + 32 + q * 8];
            f32x4 c = {0.f, 0.f, 0.f, 0.f};
            c = __builtin_amdgcn_mfma_f32_16x16x32_bf16(afr[0], bfr0, c, 0, 0, 0);
            c = __builtin_amdgcn_mfma_f32_16x16x32_bf16(afr[1], bfr1, c, 0, 0, 0);
            float tv[4];
#pragma unroll
            for (int j = 0; j < 4; ++j) tv[j] = fast_tanh(c[j]);
            if (mat < 2) {
                // transposed-C write -> row-major mat[r][n]: r = rt*16+m (col),
                // n0 = w*16 + q*4: 4 contiguous bf16 = one b64
                uint2 p2 = {pack2bf(tv[0], tv[1]), pack2bf(tv[2], tv[3])};
                short* dst = (mat == 0) ? sQ : sK;
                *(uint2*)&dst[(rt * 16 + m) * 72 + (w * 16 + q * 4)] = p2;
            } else {
                // V: straight write V^T[n][s]: n = w*16+q*4+j, s = rt*16+m
#pragma unroll
                for (int j = 0; j < 4; ++j)
                    sVt[(w * 16 + q * 4 + j) * 40 + (rt * 16 + m)] = (short)bf1(tv[j]);
            }
        }
    }
    __syncthreads();

    // ---- scores[r][s] = (Q[r]·K[s]) * rsqrt(numN): wave tile (wr, ws) ----
    const int wr = w & 1, ws = w >> 1;
    {
        float* sS = uni;  // [32][33] f32
        short8 qa0 = *(const short8*)&sQ[(wr * 16 + m) * 72 + q * 8];
        short8 qa1 = *(const short8*)&sQ[(wr * 16 + m) * 72 + 32 + q * 8];
        short8 kb0 = *(const short8*)&sK[(ws * 16 + m) * 72 + q * 8];
        short8 kb1 = *(const short8*)&sK[(ws * 16 + m) * 72 + 32 + q * 8];
        f32x4 c = {0.f, 0.f, 0.f, 0.f};
        c = __builtin_amdgcn_mfma_f32_16x16x32_bf16(qa0, kb0, c, 0, 0, 0);
        c = __builtin_amdgcn_mfma_f32_16x16x32_bf16(qa1, kb1, c, 0, 0, 0);
        float inv = rsqrtf(sNum);
#pragma unroll
        for (int j = 0; j < 4; ++j)
            sS[(wr * 16 + q * 4 + j) * 33 + ws * 16 + m] = c[j] * inv;
    }
    __syncthreads();

    // ---- softmax over s (f32, wave-parallel): thread owns (row, s) ----
    {
        const float* sS = uni;
        const int s = lane & 31, half = lane >> 5;
#pragma unroll
        for (int qq = 0; qq < 4; ++qq) {
            const int row = w + 8 * qq + 4 * half;
            float p = sS[row * 33 + s];
            float mx = p;
#pragma unroll
            for (int off = 16; off >= 1; off >>= 1) mx = fmaxf(mx, __shfl_xor(mx, off));
            float e = __expf(p - mx);
            float ds = e;
#pragma unroll
            for (int off = 16; off >= 1; off >>= 1) ds += __shfl_xor(ds, off);
            sP[row * 40 + s] = (short)bf1(e / ds);
        }
    }
    __syncthreads();

    // ---- PV: o[r][n] = sum_s attn[r][s] V[s][n]; K=32 -> 1 mfma per tile ----
    {
        short* ot = (short*)uni;  // [64][40] bf16, o^T[n][r]  (sS is dead now)
        const int rt = w & 1, ntb = (w >> 1) * 2;
        short8 pa = *(const short8*)&sP[(rt * 16 + m) * 40 + q * 8];
#pragma unroll
        for (int ni = 0; ni < 2; ++ni) {
            const int nt = ntb + ni;
            short8 vb = *(const short8*)&sVt[(nt * 16 + m) * 40 + q * 8];
            f32x4 c = {0.f, 0.f, 0.f, 0.f};
            c = __builtin_amdgcn_mfma_f32_16x16x32_bf16(pa, vb, c, 0, 0, 0);
            // transposed-C write -> ot[n][r]: n = nt*16+m, r0 = rt*16+q*4
            uint2 p2 = {pack2bf(c[0], c[1]), pack2bf(c[2], c[3])};
            *(uint2*)&ot[(nt * 16 + m) * 40 + (rt * 16 + q * 4)] = p2;
        }
    }
    __syncthreads();

    // ---- Rh[h][n] = tanh(Ao[h]·o[:,n]); R[b][h*64+n] = Rh^2 ----
    {
        const short* ot = (const short*)uni;
        short8 aa = *(const short8*)&sAo[m * 40 + q * 8];
        short8 bb = *(const short8*)&ot[(w * 16 + m) * 40 + q * 8];
        f32x4 c = {0.f, 0.f, 0.f, 0.f};
        c = __builtin_amdgcn_mfma_f32_16x16x32_bf16(aa, bb, c, 0, 0, 0);
        float* Rb = R + (size_t)b * 1024;
#pragma unroll
        for (int j = 0; j < 4; ++j) {
            float rh = fast_tanh(c[j]);
            Rb[(q * 4 + j) * 64 + w * 16 + m] = rh * rh;  // h = q*4+j, n = w*16+m
        }
    }
}

// ===== Phase 2 (ws path): assemble Rsym + graph-Laplacian. 128 envs x 8 groups =====
__global__ __launch_bounds__(256)
void att_k2(const float* __restrict__ R, float* __restrict__ out) {
    const int e  = blockIdx.x >> 3;
    const int rg = blockIdx.x & 7;
    const int t  = threadIdx.x;
    const float* Re = R + (size_t)e * 65536;
    float* Oe       = out + (size_t)e * 65536;

    const int col = t;
    const int hc = col >> 7, j = (col >> 1) & 63, pc = col & 1;

    __shared__ float red[32][4];
    float rsv[32];

#pragma unroll
    for (int rr = 0; rr < 32; ++rr) {
        const int row = rg * 32 + rr;
        const int hr = row >> 7, i = (row >> 1) & 63, pr = row & 1;
        float t1 = Re[i * 1024 + j * 16 + hr * 8 + hc * 4 + pr * 2 + pc];
        float t2 = Re[j * 1024 + i * 16 + hc * 8 + hr * 4 + pc * 2 + pr];
        float rs = t1 + t2;
        rsv[rr] = rs;
        float sum = rs;
#pragma unroll
        for (int off = 32; off >= 1; off >>= 1) sum += __shfl_xor(sum, off);
        if ((t & 63) == 0) red[rr][t >> 6] = sum;
    }
    __syncthreads();
#pragma unroll
    for (int rr = 0; rr < 32; ++rr) {
        const int row = rg * 32 + rr;
        float tot = red[rr][0] + red[rr][1] + red[rr][2] + red[rr][3];
        Oe[row * 256 + col] = (col == row) ? tot : -rsv[rr];
    }
}

// ===== Fallback path (tiny ws): old VALU kernel w/ atomic scatter + Laplacian =====
__global__ __launch_bounds__(256, 4)
void att_k1_atomic(const float* __restrict__ x, const float* __restrict__ L,
                   const float* __restrict__ Aq, const float* __restrict__ Ak,
                   const float* __restrict__ Av, const float* __restrict__ Ao,
                   float* __restrict__ out) {
    const int b    = blockIdx.x;
    const int t    = threadIdx.x;
    const int lane = t & 63;
    const int w    = t >> 6;
    const int wu   = __builtin_amdgcn_readfirstlane(w);

    __shared__ float sQ[32][68];
    __shared__ float sK[32][68];
    __shared__ float sV[32][68];
    __shared__ float sNum;

    const float* xb = x + (size_t)b * 4096;
    if (t < 64) {
        float lv = L[(size_t)b * 64 + t];
        unsigned long long mk = __ballot(lv >= 1.0f);
        if (t == 0) sNum = (float)__popcll(mk) + 1.0f;
    }
    float acc[3][8];
#pragma unroll
    for (int mm = 0; mm < 3; ++mm)
#pragma unroll
        for (int k = 0; k < 8; ++k) acc[mm][k] = 0.f;
    const float* Am[3] = {Aq, Ak, Av};
#pragma unroll
    for (int hf = 0; hf < 2; ++hf) {
        float xv[32];
#pragma unroll
        for (int d = 0; d < 32; ++d) xv[d] = xb[(hf * 32 + d) * 64 + lane];
#pragma unroll
        for (int mm = 0; mm < 3; ++mm)
#pragma unroll
            for (int k = 0; k < 8; ++k) {
                const float* Ar = Am[mm] + (wu + 4 * k) * 64 + hf * 32;
                float a = acc[mm][k];
#pragma unroll
                for (int d = 0; d < 32; ++d) a = fmaf(Ar[d], xv[d], a);
                acc[mm][k] = a;
            }
    }
    float(*const sMat[3])[68] = {sQ, sK, sV};
#pragma unroll
    for (int mm = 0; mm < 3; ++mm)
#pragma unroll
        for (int k = 0; k < 8; ++k)
            sMat[mm][wu + 4 * k][lane] = fast_tanh(acc[mm][k]);
    __syncthreads();

    const int s = lane & 31, half = lane >> 5;
    const float inv = rsqrtf(sNum);
    float kreg[32];
#pragma unroll
    for (int c = 0; c < 8; ++c) {
        float4 kv = *(const float4*)&sK[s][half * 32 + 4 * c];
        kreg[4 * c] = kv.x; kreg[4 * c + 1] = kv.y;
        kreg[4 * c + 2] = kv.z; kreg[4 * c + 3] = kv.w;
    }
    float sc8[8];
#pragma unroll
    for (int kk = 0; kk < 8; ++kk) {
        float sc = 0.f;
#pragma unroll
        for (int c = 0; c < 8; ++c) {
            float4 qv = *(const float4*)&sQ[wu + 4 * kk][half * 32 + 4 * c];
            sc = fmaf(qv.x, kreg[4 * c], sc);
            sc = fmaf(qv.y, kreg[4 * c + 1], sc);
            sc = fmaf(qv.z, kreg[4 * c + 2], sc);
            sc = fmaf(qv.w, kreg[4 * c + 3], sc);
        }
        sc += __shfl_xor(sc, 32);
        sc8[kk] = sc * inv;
    }
    float pown[4];
#pragma unroll
    for (int qq = 0; qq < 4; ++qq) pown[qq] = half ? sc8[2 * qq + 1] : sc8[2 * qq];
#pragma unroll
    for (int qq = 0; qq < 4; ++qq) {
        float mx = pown[qq];
#pragma unroll
        for (int off = 16; off >= 1; off >>= 1) mx = fmaxf(mx, __shfl_xor(mx, off));
        float e = __expf(pown[qq] - mx);
        float ds = e;
#pragma unroll
        for (int off = 16; off >= 1; off >>= 1) ds += __shfl_xor(ds, off);
        pown[qq] = e / ds;
    }
    __syncthreads();
#pragma unroll
    for (int qq = 0; qq < 4; ++qq) sQ[wu + 8 * qq + 4 * half][s] = pown[qq];
    __syncthreads();
    float oacc[8];
#pragma unroll
    for (int k = 0; k < 8; ++k) oacc[k] = 0.f;
#pragma unroll
    for (int sb = 0; sb < 8; ++sb) {
        float4 arow[8];
#pragma unroll
        for (int kk = 0; kk < 8; ++kk) arow[kk] = *(const float4*)&sQ[wu + 4 * kk][4 * sb];
#pragma unroll
        for (int ds2 = 0; ds2 < 4; ++ds2) {
            float vv = sV[4 * sb + ds2][lane];
#pragma unroll
            for (int kk = 0; kk < 8; ++kk) {
                float a = (ds2 == 0) ? arow[kk].x : (ds2 == 1) ? arow[kk].y
                        : (ds2 == 2) ? arow[kk].z : arow[kk].w;
                oacc[kk] = fmaf(a, vv, oacc[kk]);
            }
        }
    }
#pragma unroll
    for (int k = 0; k < 8; ++k) sK[wu + 4 * k][lane] = oacc[k];
    __syncthreads();
    float col[32];
#pragma unroll
    for (int r = 0; r < 32; ++r) col[r] = sK[r][lane];
#pragma unroll
    for (int k = 0; k < 4; ++k) {
        const int h = wu + 4 * k;
        const float* AoR = Ao + h * 32;
        float a2 = 0.f;
#pragma unroll
        for (int r = 0; r < 32; ++r) a2 = fmaf(AoR[r], col[r], a2);
        float rh = fast_tanh(a2);
        float val = rh * rh;
        const int e = b >> 6, i = b & 63;
        const int c = h * 64 + lane;
        const int jj = c >> 4, k4 = c & 15;
        const int hr = (k4 >> 3) & 1, hc = (k4 >> 2) & 1;
        const int pr = (k4 >> 1) & 1, pc = k4 & 1;
        const int row = hr * 128 + 2 * i + pr;
        const int colo = hc * 128 + 2 * jj + pc;
        float* oe = out + (size_t)e * 65536;
        atomicAdd(&oe[row * 256 + colo], val);
        atomicAdd(&oe[colo * 256 + row], val);
    }
}

__global__ __launch_bounds__(256)
void att_k3(float* __restrict__ out) {
    const size_t rowbase = (size_t)blockIdx.x * 256;
    const int t = threadIdx.x;
    float v = out[rowbase + t];
    float sum = v;
#pragma unroll
    for (int off = 32; off >= 1; off >>= 1) sum += __shfl_xor(sum, off);
    __shared__ float red[4];
    if ((t & 63) == 0) red[t >> 6] = sum;
    __syncthreads();
    float tot = red[0] + red[1] + red[2] + red[3];
    const int row = blockIdx.x & 255;
    out[rowbase + t] = (t == row) ? tot : -v;
}

extern "C" void kernel_launch(void* const* d_in, const int* in_sizes, int n_in,
                              void* d_out, int out_size, void* d_ws, size_t ws_size,
                              hipStream_t stream) {
    const float* x  = (const float*)d_in[0];
    const float* L  = (const float*)d_in[1];
    const float* Aq = (const float*)d_in[2];
    const float* Ak = (const float*)d_in[3];
    const float* Av = (const float*)d_in[4];
    const float* Ao = (const float*)d_in[5];
    float* out = (float*)d_out;

    const size_t need = (size_t)Bn * 1024 * sizeof(float);
    if (ws_size >= need) {
        float* R = (float*)d_ws;
        att_m1<<<Bn, 256, 0, stream>>>(x, L, Aq, Ak, Av, Ao, R);
        att_k2<<<Ee * 8, 256, 0, stream>>>(R, out);
    } else {
        (void)hipMemsetAsync(d_out, 0, (size_t)out_size * sizeof(float), stream);
        att_k1_atomic<<<Bn, 256, 0, stream>>>(x, L, Aq, Ak, Av, Ao, out);
        att_k3<<<Ee * 256, 256, 0, stream>>>(out);
    }
}

// Round 5
// 92.375 us; speedup vs baseline: 2.6551x; 1.0468x over previous
//
#include <hip/hip_runtime.h>
#include <math.h>

#define Bn 8192
#define Ee 128

typedef __attribute__((ext_vector_type(8))) short short8;   // 8 bf16 (4 VGPR) MFMA A/B frag
typedef __attribute__((ext_vector_type(4))) float f32x4;    // MFMA C/D frag

__device__ __forceinline__ float fast_tanh(float x) {
    x = fminf(fmaxf(x, -15.f), 15.f);
    float e = __expf(2.f * x);
    return (e - 1.f) / (e + 1.f);
}

__device__ __forceinline__ unsigned int bf1(float a) {
    return (__builtin_bit_cast(unsigned int, a) + 0x8000u) >> 16;
}
__device__ __forceinline__ unsigned int pack2bf(float a, float b) {
    unsigned int ua = (__builtin_bit_cast(unsigned int, a) + 0x8000u) >> 16;
    unsigned int ub = (__builtin_bit_cast(unsigned int, b) + 0x8000u) & 0xffff0000u;
    return ua | ub;
}

// ---- prep: one-shot f32->bf16 conversion of Aq/Ak/Av (3x[32][64]) + Ao ([16][32])
// into ws. Layout (shorts): Abf[mat*2048 + r*64 + d], Aobf at offset 6144: [h*32 + r].
__global__ __launch_bounds__(256)
void att_prep(const float* __restrict__ Aq, const float* __restrict__ Ak,
              const float* __restrict__ Av, const float* __restrict__ Ao,
              short* __restrict__ Abf) {
    const int t = threadIdx.x;
    const float* Am[3] = {Aq, Ak, Av};
#pragma unroll
    for (int mat = 0; mat < 3; ++mat) {
        float4 v0 = *(const float4*)(Am[mat] + t * 8);
        float4 v1 = *(const float4*)(Am[mat] + t * 8 + 4);
        uint4 pk = {pack2bf(v0.x, v0.y), pack2bf(v0.z, v0.w),
                    pack2bf(v1.x, v1.y), pack2bf(v1.z, v1.w)};
        *(uint4*)&Abf[mat * 2048 + t * 8] = pk;
    }
    if (t < 64) {
        float4 v0 = *(const float4*)(Ao + t * 8);
        float4 v1 = *(const float4*)(Ao + t * 8 + 4);
        uint4 pk = {pack2bf(v0.x, v0.y), pack2bf(v0.z, v0.w),
                    pack2bf(v1.x, v1.y), pack2bf(v1.z, v1.w)};
        *(uint4*)&Abf[6144 + t * 8] = pk;
    }
}

// ============================ MFMA main kernel ============================
// One block per batch element b. 4 waves. All GEMMs on 16x16x32 bf16 MFMA.
// A-frag: row=lane&15, k=(lane>>4)*8+j. B-frag: col=lane&15, k=(lane>>4)*8+j.
// C/D: col=lane&15, row=(lane>>4)*4+reg (verified layouts).
__global__ __launch_bounds__(256, 6)
void att_m1(const float* __restrict__ x, const float* __restrict__ L,
            const short* __restrict__ Abf, float* __restrict__ R) {
    const int b    = blockIdx.x;
    const int t    = threadIdx.x;
    const int lane = t & 63;
    const int w    = t >> 6;        // wave 0..3
    const int q    = lane >> 4;     // quarter 0..3
    const int m    = lane & 15;

    __shared__ __align__(16) short sQ[32 * 72];      // Q bf16 [r][n], 144B rows
    __shared__ __align__(16) short sK[32 * 72];      // K bf16 [s][n]
    __shared__ __align__(16) short sVt[64 * 40];     // V^T bf16 [n][s], 80B rows
    __shared__ __align__(16) short sP[32 * 40];      // attn bf16 [r][s]
    __shared__ __align__(16) float uni[1320];        // union: sS f32[32][33] | ot bf16[64][40]
    __shared__ float sNum;

    // ---- x column loads (A-frags for QKV): lane holds x[kc*32+q*8+j][w*16+m] ----
    float xf[16];
    {
        const float* p0 = x + (size_t)b * 4096 + (q * 8) * 64 + (w * 16 + m);
#pragma unroll
        for (int j = 0; j < 8; ++j) xf[j] = p0[j * 64];
        const float* p1 = p0 + 32 * 64;
#pragma unroll
        for (int j = 0; j < 8; ++j) xf[8 + j] = p1[j * 64];
    }

    // ---- numN = count(L[b,0,:] >= 1) + 1 ----
    if (t < 64) {
        float lv = L[(size_t)b * 64 + t];
        unsigned long long mk = __ballot(lv >= 1.0f);
        if (t == 0) sNum = (float)__popcll(mk) + 1.0f;
    }

    // ---- QKV (transposed GEMM): D[n][r] = sum_d x[d][n] * Am[r][d] ----
    short8 afr[2];
    {
        uint4 pk0 = {pack2bf(xf[0], xf[1]), pack2bf(xf[2], xf[3]),
                     pack2bf(xf[4], xf[5]), pack2bf(xf[6], xf[7])};
        uint4 pk1 = {pack2bf(xf[8], xf[9]), pack2bf(xf[10], xf[11]),
                     pack2bf(xf[12], xf[13]), pack2bf(xf[14], xf[15])};
        afr[0] = __builtin_bit_cast(short8, pk0);
        afr[1] = __builtin_bit_cast(short8, pk1);
    }
#pragma unroll
    for (int mat = 0; mat < 3; ++mat) {
#pragma unroll
        for (int rt = 0; rt < 2; ++rt) {
            const short* Ab = Abf + mat * 2048 + (rt * 16 + m) * 64 + q * 8;
            short8 bfr0 = *(const short8*)Ab;          // d = q*8..+8
            short8 bfr1 = *(const short8*)(Ab + 32);   // d = 32+q*8..+8
            f32x4 c = {0.f, 0.f, 0.f, 0.f};
            c = __builtin_amdgcn_mfma_f32_16x16x32_bf16(afr[0], bfr0, c, 0, 0, 0);
            c = __builtin_amdgcn_mfma_f32_16x16x32_bf16(afr[1], bfr1, c, 0, 0, 0);
            float tv[4];
#pragma unroll
            for (int j = 0; j < 4; ++j) tv[j] = fast_tanh(c[j]);
            if (mat < 2) {
                // C^T write -> row-major mat[r][n]: r = rt*16+m, n0 = w*16+q*4
                uint2 p2 = {pack2bf(tv[0], tv[1]), pack2bf(tv[2], tv[3])};
                short* dst = (mat == 0) ? sQ : sK;
                *(uint2*)&dst[(rt * 16 + m) * 72 + (w * 16 + q * 4)] = p2;
            } else {
                // V: straight write V^T[n][s]: n = w*16+q*4+j, s = rt*16+m
#pragma unroll
                for (int j = 0; j < 4; ++j)
                    sVt[(w * 16 + q * 4 + j) * 40 + (rt * 16 + m)] = (short)bf1(tv[j]);
            }
        }
    }
    __syncthreads();

    // ---- scores[r][s] = (Q[r]·K[s]) * rsqrt(numN): wave tile (wr, ws) ----
    const int wr = w & 1, ws = w >> 1;
    {
        float* sS = uni;  // [32][33] f32
        short8 qa0 = *(const short8*)&sQ[(wr * 16 + m) * 72 + q * 8];
        short8 qa1 = *(const short8*)&sQ[(wr * 16 + m) * 72 + 32 + q * 8];
        short8 kb0 = *(const short8*)&sK[(ws * 16 + m) * 72 + q * 8];
        short8 kb1 = *(const short8*)&sK[(ws * 16 + m) * 72 + 32 + q * 8];
        f32x4 c = {0.f, 0.f, 0.f, 0.f};
        c = __builtin_amdgcn_mfma_f32_16x16x32_bf16(qa0, kb0, c, 0, 0, 0);
        c = __builtin_amdgcn_mfma_f32_16x16x32_bf16(qa1, kb1, c, 0, 0, 0);
        float inv = rsqrtf(sNum);
#pragma unroll
        for (int j = 0; j < 4; ++j)
            sS[(wr * 16 + q * 4 + j) * 33 + ws * 16 + m] = c[j] * inv;
    }
    __syncthreads();

    // ---- softmax over s (f32, wave-parallel) ----
    {
        const float* sS = uni;
        const int s = lane & 31, half = lane >> 5;
#pragma unroll
        for (int qq = 0; qq < 4; ++qq) {
            const int row = w + 8 * qq + 4 * half;
            float p = sS[row * 33 + s];
            float mx = p;
#pragma unroll
            for (int off = 16; off >= 1; off >>= 1) mx = fmaxf(mx, __shfl_xor(mx, off));
            float e = __expf(p - mx);
            float ds = e;
#pragma unroll
            for (int off = 16; off >= 1; off >>= 1) ds += __shfl_xor(ds, off);
            sP[row * 40 + s] = (short)bf1(e / ds);
        }
    }
    __syncthreads();

    // ---- PV: o[r][n] = sum_s attn[r][s] V[s][n] ----
    {
        short* ot = (short*)uni;  // [64][40] bf16, o^T[n][r] (sS dead)
        const int rt = w & 1, ntb = (w >> 1) * 2;
        short8 pa = *(const short8*)&sP[(rt * 16 + m) * 40 + q * 8];
#pragma unroll
        for (int ni = 0; ni < 2; ++ni) {
            const int nt = ntb + ni;
            short8 vb = *(const short8*)&sVt[(nt * 16 + m) * 40 + q * 8];
            f32x4 c = {0.f, 0.f, 0.f, 0.f};
            c = __builtin_amdgcn_mfma_f32_16x16x32_bf16(pa, vb, c, 0, 0, 0);
            uint2 p2 = {pack2bf(c[0], c[1]), pack2bf(c[2], c[3])};
            *(uint2*)&ot[(nt * 16 + m) * 40 + (rt * 16 + q * 4)] = p2;
        }
    }
    __syncthreads();

    // ---- Rh[h][n] = tanh(Ao[h]·o[:,n]); R[b][h*64+n] = Rh^2 ----
    {
        const short* ot = (const short*)uni;
        short8 aa = *(const short8*)&Abf[6144 + m * 32 + q * 8];
        short8 bb = *(const short8*)&ot[(w * 16 + m) * 40 + q * 8];
        f32x4 c = {0.f, 0.f, 0.f, 0.f};
        c = __builtin_amdgcn_mfma_f32_16x16x32_bf16(aa, bb, c, 0, 0, 0);
        float* Rb = R + (size_t)b * 1024;
#pragma unroll
        for (int j = 0; j < 4; ++j) {
            float rh = fast_tanh(c[j]);
            Rb[(q * 4 + j) * 64 + w * 16 + m] = rh * rh;  // h = q*4+j, n = w*16+m
        }
    }
}

// ===== Phase 2: coalesced Rsym + Laplacian.
// out[row][col] = -(Rupper[row][col]) off-diag; out[row][row] = full rowsum.
// Rupper[row][col] = R[e][i][j*16+8hr+4hc+2pr+pc] + R[e][j][i*16+8hc+4hr+2pc+pr].
// Block = 4 rows (one per wave); lane j owns the 4 (hc,pc) cells of column group j.
__global__ __launch_bounds__(256)
void att_k2(const float* __restrict__ R, float* __restrict__ out) {
    const int e   = blockIdx.x >> 6;
    const int rg  = blockIdx.x & 63;
    const int w   = threadIdx.x >> 6;
    const int j   = threadIdx.x & 63;
    const int row = rg * 4 + w;
    const int hr = row >> 7, i = (row >> 1) & 63, pr = row & 1;

    const float* Re = R + (size_t)e * 65536;
    float* Oe       = out + (size_t)e * 65536;

    // t1: one 64B line R[i][j*16 ..]
    const float* t1p = Re + i * 1024 + j * 16 + 8 * hr + 2 * pr;
    float2 t1a = *(const float2*)t1p;        // (hc=0, pc=0/1)
    float2 t1b = *(const float2*)(t1p + 4);  // (hc=1, pc=0/1)
    // t2: 4 dwords from line R[j][i*16 ..]
    const float* t2p = Re + j * 1024 + i * 16 + 4 * hr + pr;
    float c00 = t1a.x + t2p[0];
    float c01 = t1a.y + t2p[2];
    float c10 = t1b.x + t2p[8];
    float c11 = t1b.y + t2p[10];

    float sum = c00 + c01 + c10 + c11;
#pragma unroll
    for (int off = 32; off >= 1; off >>= 1) sum += __shfl_xor(sum, off);  // full rowsum

    // diagonal lands at lane j==i, cell (hc==hr, pc==pr)
    float v00 = -c00, v01 = -c01, v10 = -c10, v11 = -c11;
    if (j == i) {
        if (hr == 0) { if (pr == 0) v00 = sum; else v01 = sum; }
        else         { if (pr == 0) v10 = sum; else v11 = sum; }
    }
    float2 z0 = {v00, v01}, z1 = {v10, v11};
    *(float2*)&Oe[row * 256 + 2 * j]       = z0;
    *(float2*)&Oe[row * 256 + 128 + 2 * j] = z1;
}

// ===== Fallback path (tiny ws): VALU kernel w/ atomic scatter + Laplacian =====
__global__ __launch_bounds__(256, 4)
void att_k1_atomic(const float* __restrict__ x, const float* __restrict__ L,
                   const float* __restrict__ Aq, const float* __restrict__ Ak,
                   const float* __restrict__ Av, const float* __restrict__ Ao,
                   float* __restrict__ out) {
    const int b    = blockIdx.x;
    const int t    = threadIdx.x;
    const int lane = t & 63;
    const int w    = t >> 6;
    const int wu   = __builtin_amdgcn_readfirstlane(w);

    __shared__ float sQ[32][68];
    __shared__ float sK[32][68];
    __shared__ float sV[32][68];
    __shared__ float sNum;

    const float* xb = x + (size_t)b * 4096;
    if (t < 64) {
        float lv = L[(size_t)b * 64 + t];
        unsigned long long mk = __ballot(lv >= 1.0f);
        if (t == 0) sNum = (float)__popcll(mk) + 1.0f;
    }
    float acc[3][8];
#pragma unroll
    for (int mm = 0; mm < 3; ++mm)
#pragma unroll
        for (int k = 0; k < 8; ++k) acc[mm][k] = 0.f;
    const float* Am[3] = {Aq, Ak, Av};
#pragma unroll
    for (int hf = 0; hf < 2; ++hf) {
        float xv[32];
#pragma unroll
        for (int d = 0; d < 32; ++d) xv[d] = xb[(hf * 32 + d) * 64 + lane];
#pragma unroll
        for (int mm = 0; mm < 3; ++mm)
#pragma unroll
            for (int k = 0; k < 8; ++k) {
                const float* Ar = Am[mm] + (wu + 4 * k) * 64 + hf * 32;
                float a = acc[mm][k];
#pragma unroll
                for (int d = 0; d < 32; ++d) a = fmaf(Ar[d], xv[d], a);
                acc[mm][k] = a;
            }
    }
    float(*const sMat[3])[68] = {sQ, sK, sV};
#pragma unroll
    for (int mm = 0; mm < 3; ++mm)
#pragma unroll
        for (int k = 0; k < 8; ++k)
            sMat[mm][wu + 4 * k][lane] = fast_tanh(acc[mm][k]);
    __syncthreads();

    const int s = lane & 31, half = lane >> 5;
    const float inv = rsqrtf(sNum);
    float kreg[32];
#pragma unroll
    for (int c = 0; c < 8; ++c) {
        float4 kv = *(const float4*)&sK[s][half * 32 + 4 * c];
        kreg[4 * c] = kv.x; kreg[4 * c + 1] = kv.y;
        kreg[4 * c + 2] = kv.z; kreg[4 * c + 3] = kv.w;
    }
    float sc8[8];
#pragma unroll
    for (int kk = 0; kk < 8; ++kk) {
        float sc = 0.f;
#pragma unroll
        for (int c = 0; c < 8; ++c) {
            float4 qv = *(const float4*)&sQ[wu + 4 * kk][half * 32 + 4 * c];
            sc = fmaf(qv.x, kreg[4 * c], sc);
            sc = fmaf(qv.y, kreg[4 * c + 1], sc);
            sc = fmaf(qv.z, kreg[4 * c + 2], sc);
            sc = fmaf(qv.w, kreg[4 * c + 3], sc);
        }
        sc += __shfl_xor(sc, 32);
        sc8[kk] = sc * inv;
    }
    float pown[4];
#pragma unroll
    for (int qq = 0; qq < 4; ++qq) pown[qq] = half ? sc8[2 * qq + 1] : sc8[2 * qq];
#pragma unroll
    for (int qq = 0; qq < 4; ++qq) {
        float mx = pown[qq];
#pragma unroll
        for (int off = 16; off >= 1; off >>= 1) mx = fmaxf(mx, __shfl_xor(mx, off));
        float e = __expf(pown[qq] - mx);
        float ds = e;
#pragma unroll
        for (int off = 16; off >= 1; off >>= 1) ds += __shfl_xor(ds, off);
        pown[qq] = e / ds;
    }
    __syncthreads();
#pragma unroll
    for (int qq = 0; qq < 4; ++qq) sQ[wu + 8 * qq + 4 * half][s] = pown[qq];
    __syncthreads();
    float oacc[8];
#pragma unroll
    for (int k = 0; k < 8; ++k) oacc[k] = 0.f;
#pragma unroll
    for (int sb = 0; sb < 8; ++sb) {
        float4 arow[8];
#pragma unroll
        for (int kk = 0; kk < 8; ++kk) arow[kk] = *(const float4*)&sQ[wu + 4 * kk][4 * sb];
#pragma unroll
        for (int ds2 = 0; ds2 < 4; ++ds2) {
            float vv = sV[4 * sb + ds2][lane];
#pragma unroll
            for (int kk = 0; kk < 8; ++kk) {
                float a = (ds2 == 0) ? arow[kk].x : (ds2 == 1) ? arow[kk].y
                        : (ds2 == 2) ? arow[kk].z : arow[kk].w;
                oacc[kk] = fmaf(a, vv, oacc[kk]);
            }
        }
    }
#pragma unroll
    for (int k = 0; k < 8; ++k) sK[wu + 4 * k][lane] = oacc[k];
    __syncthreads();
    float col[32];
#pragma unroll
    for (int r = 0; r < 32; ++r) col[r] = sK[r][lane];
#pragma unroll
    for (int k = 0; k < 4; ++k) {
        const int h = wu + 4 * k;
        const float* AoR = Ao + h * 32;
        float a2 = 0.f;
#pragma unroll
        for (int r = 0; r < 32; ++r) a2 = fmaf(AoR[r], col[r], a2);
        float rh = fast_tanh(a2);
        float val = rh * rh;
        const int e = b >> 6, i = b & 63;
        const int c = h * 64 + lane;
        const int jj = c >> 4, k4 = c & 15;
        const int hr = (k4 >> 3) & 1, hc = (k4 >> 2) & 1;
        const int pr = (k4 >> 1) & 1, pc = k4 & 1;
        const int row = hr * 128 + 2 * i + pr;
        const int colo = hc * 128 + 2 * jj + pc;
        float* oe = out + (size_t)e * 65536;
        atomicAdd(&oe[row * 256 + colo], val);
        atomicAdd(&oe[colo * 256 + row], val);
    }
}

__global__ __launch_bounds__(256)
void att_k3(float* __restrict__ out) {
    const size_t rowbase = (size_t)blockIdx.x * 256;
    const int t = threadIdx.x;
    float v = out[rowbase + t];
    float sum = v;
#pragma unroll
    for (int off = 32; off >= 1; off >>= 1) sum += __shfl_xor(sum, off);
    __shared__ float red[4];
    if ((t & 63) == 0) red[t >> 6] = sum;
    __syncthreads();
    float tot = red[0] + red[1] + red[2] + red[3];
    const int row = blockIdx.x & 255;
    out[rowbase + t] = (t == row) ? tot : -v;
}

extern "C" void kernel_launch(void* const* d_in, const int* in_sizes, int n_in,
                              void* d_out, int out_size, void* d_ws, size_t ws_size,
                              hipStream_t stream) {
    const float* x  = (const float*)d_in[0];
    const float* L  = (const float*)d_in[1];
    const float* Aq = (const float*)d_in[2];
    const float* Ak = (const float*)d_in[3];
    const float* Av = (const float*)d_in[4];
    const float* Ao = (const float*)d_in[5];
    float* out = (float*)d_out;

    const size_t rbytes = (size_t)Bn * 1024 * sizeof(float);
    const size_t need   = rbytes + 6656 * sizeof(short);
    if (ws_size >= need) {
        float* R   = (float*)d_ws;
        short* Abf = (short*)((char*)d_ws + rbytes);
        att_prep<<<1, 256, 0, stream>>>(Aq, Ak, Av, Ao, Abf);
        att_m1<<<Bn, 256, 0, stream>>>(x, L, Abf, R);
        att_k2<<<Ee * 64, 256, 0, stream>>>(R, out);
    } else {
        (void)hipMemsetAsync(d_out, 0, (size_t)out_size * sizeof(float), stream);
        att_k1_atomic<<<Bn, 256, 0, stream>>>(x, L, Aq, Ak, Av, Ao, out);
        att_k3<<<Ee * 256, 256, 0, stream>>>(out);
    }
}

// Round 6
// 90.376 us; speedup vs baseline: 2.7138x; 1.0221x over previous
//
#include <hip/hip_runtime.h>
#include <math.h>

#define Bn 8192
#define Ee 128

typedef __attribute__((ext_vector_type(8))) short short8;   // 8 bf16 (4 VGPR) MFMA A/B frag
typedef __attribute__((ext_vector_type(4))) float f32x4;    // MFMA C/D frag

// tanh(x) = 1 - 2/(1+e^{2x}).  v_exp-based, v_rcp (~1ulp) division, no clamp
// needed: x->+inf => e=inf, rcp=0 => 1; x->-inf => e=0 => -1. bf16-accuracy ok.
__device__ __forceinline__ float fast_tanh(float x) {
    float e = __expf(2.f * x);
    return fmaf(-2.f, __builtin_amdgcn_rcpf(1.f + e), 1.f);
}

__device__ __forceinline__ unsigned int bf1(float a) {
    return (__builtin_bit_cast(unsigned int, a) + 0x8000u) >> 16;
}
__device__ __forceinline__ unsigned int pack2bf(float a, float b) {
    unsigned int ua = (__builtin_bit_cast(unsigned int, a) + 0x8000u) >> 16;
    unsigned int ub = (__builtin_bit_cast(unsigned int, b) + 0x8000u) & 0xffff0000u;
    return ua | ub;
}

// ---- prep: one-shot f32->bf16 conversion of Aq/Ak/Av (3x[32][64]) + Ao ([16][32])
// into ws. Layout (shorts): Abf[mat*2048 + r*64 + d], Aobf at offset 6144: [h*32 + r].
__global__ __launch_bounds__(256)
void att_prep(const float* __restrict__ Aq, const float* __restrict__ Ak,
              const float* __restrict__ Av, const float* __restrict__ Ao,
              short* __restrict__ Abf) {
    const int t = threadIdx.x;
    const float* Am[3] = {Aq, Ak, Av};
#pragma unroll
    for (int mat = 0; mat < 3; ++mat) {
        float4 v0 = *(const float4*)(Am[mat] + t * 8);
        float4 v1 = *(const float4*)(Am[mat] + t * 8 + 4);
        uint4 pk = {pack2bf(v0.x, v0.y), pack2bf(v0.z, v0.w),
                    pack2bf(v1.x, v1.y), pack2bf(v1.z, v1.w)};
        *(uint4*)&Abf[mat * 2048 + t * 8] = pk;
    }
    if (t < 64) {
        float4 v0 = *(const float4*)(Ao + t * 8);
        float4 v1 = *(const float4*)(Ao + t * 8 + 4);
        uint4 pk = {pack2bf(v0.x, v0.y), pack2bf(v0.z, v0.w),
                    pack2bf(v1.x, v1.y), pack2bf(v1.z, v1.w)};
        *(uint4*)&Abf[6144 + t * 8] = pk;
    }
}

// ============================ MFMA main kernel ============================
// One block per batch element b. 4 waves. All GEMMs on 16x16x32 bf16 MFMA.
// A-frag: row=lane&15, k=(lane>>4)*8+j. B-frag: col=lane&15, k=(lane>>4)*8+j.
// C/D: col=lane&15, row=(lane>>4)*4+reg (verified layouts).
__global__ __launch_bounds__(256, 6)
void att_m1(const float* __restrict__ x, const float* __restrict__ L,
            const short* __restrict__ Abf, float* __restrict__ R) {
    const int b    = blockIdx.x;
    const int t    = threadIdx.x;
    const int lane = t & 63;
    const int w    = t >> 6;        // wave 0..3
    const int q    = lane >> 4;     // quarter 0..3
    const int m    = lane & 15;

    __shared__ __align__(16) short sQ[32 * 72];      // Q bf16 [r][n], 144B rows
    __shared__ __align__(16) short sK[32 * 72];      // K bf16 [s][n]
    __shared__ __align__(16) short sVt[64 * 40];     // V^T bf16 [n][s], 80B rows
    __shared__ __align__(16) short sP[32 * 40];      // attn bf16 [r][s]
    __shared__ __align__(16) float uni[1320];        // union: sS f32[32][33] | ot bf16[64][40]
    __shared__ float sNum;

    // ---- x column loads (A-frags for QKV): lane holds x[kc*32+q*8+j][w*16+m] ----
    float xf[16];
    {
        const float* p0 = x + (size_t)b * 4096 + (q * 8) * 64 + (w * 16 + m);
#pragma unroll
        for (int j = 0; j < 8; ++j) xf[j] = p0[j * 64];
        const float* p1 = p0 + 32 * 64;
#pragma unroll
        for (int j = 0; j < 8; ++j) xf[8 + j] = p1[j * 64];
    }

    // ---- numN = count(L[b,0,:] >= 1) + 1 ----
    if (t < 64) {
        float lv = L[(size_t)b * 64 + t];
        unsigned long long mk = __ballot(lv >= 1.0f);
        if (t == 0) sNum = (float)__popcll(mk) + 1.0f;
    }

    // ---- QKV (transposed GEMM): D[n][r] = sum_d x[d][n] * Am[r][d] ----
    short8 afr[2];
    {
        uint4 pk0 = {pack2bf(xf[0], xf[1]), pack2bf(xf[2], xf[3]),
                     pack2bf(xf[4], xf[5]), pack2bf(xf[6], xf[7])};
        uint4 pk1 = {pack2bf(xf[8], xf[9]), pack2bf(xf[10], xf[11]),
                     pack2bf(xf[12], xf[13]), pack2bf(xf[14], xf[15])};
        afr[0] = __builtin_bit_cast(short8, pk0);
        afr[1] = __builtin_bit_cast(short8, pk1);
    }
#pragma unroll
    for (int mat = 0; mat < 3; ++mat) {
#pragma unroll
        for (int rt = 0; rt < 2; ++rt) {
            const short* Ab = Abf + mat * 2048 + (rt * 16 + m) * 64 + q * 8;
            short8 bfr0 = *(const short8*)Ab;          // d = q*8..+8
            short8 bfr1 = *(const short8*)(Ab + 32);   // d = 32+q*8..+8
            f32x4 c = {0.f, 0.f, 0.f, 0.f};
            c = __builtin_amdgcn_mfma_f32_16x16x32_bf16(afr[0], bfr0, c, 0, 0, 0);
            c = __builtin_amdgcn_mfma_f32_16x16x32_bf16(afr[1], bfr1, c, 0, 0, 0);
            float tv[4];
#pragma unroll
            for (int j = 0; j < 4; ++j) tv[j] = fast_tanh(c[j]);
            if (mat < 2) {
                // C^T write -> row-major mat[r][n]: r = rt*16+m, n0 = w*16+q*4
                uint2 p2 = {pack2bf(tv[0], tv[1]), pack2bf(tv[2], tv[3])};
                short* dst = (mat == 0) ? sQ : sK;
                *(uint2*)&dst[(rt * 16 + m) * 72 + (w * 16 + q * 4)] = p2;
            } else {
                // V: straight write V^T[n][s]: n = w*16+q*4+j, s = rt*16+m
#pragma unroll
                for (int j = 0; j < 4; ++j)
                    sVt[(w * 16 + q * 4 + j) * 40 + (rt * 16 + m)] = (short)bf1(tv[j]);
            }
        }
    }
    __syncthreads();

    // ---- scores[r][s] = (Q[r]·K[s]) * rsqrt(numN): wave tile (wr, ws) ----
    const int wr = w & 1, ws = w >> 1;
    {
        float* sS = uni;  // [32][33] f32
        short8 qa0 = *(const short8*)&sQ[(wr * 16 + m) * 72 + q * 8];
        short8 qa1 = *(const short8*)&sQ[(wr * 16 + m) * 72 + 32 + q * 8];
        short8 kb0 = *(const short8*)&sK[(ws * 16 + m) * 72 + q * 8];
        short8 kb1 = *(const short8*)&sK[(ws * 16 + m) * 72 + 32 + q * 8];
        f32x4 c = {0.f, 0.f, 0.f, 0.f};
        c = __builtin_amdgcn_mfma_f32_16x16x32_bf16(qa0, kb0, c, 0, 0, 0);
        c = __builtin_amdgcn_mfma_f32_16x16x32_bf16(qa1, kb1, c, 0, 0, 0);
        float inv = rsqrtf(sNum);
#pragma unroll
        for (int j = 0; j < 4; ++j)
            sS[(wr * 16 + q * 4 + j) * 33 + ws * 16 + m] = c[j] * inv;
    }
    __syncthreads();

    // ---- softmax over s (f32, wave-parallel) ----
    {
        const float* sS = uni;
        const int s = lane & 31, half = lane >> 5;
#pragma unroll
        for (int qq = 0; qq < 4; ++qq) {
            const int row = w + 8 * qq + 4 * half;
            float p = sS[row * 33 + s];
            float mx = p;
#pragma unroll
            for (int off = 16; off >= 1; off >>= 1) mx = fmaxf(mx, __shfl_xor(mx, off));
            float e = __expf(p - mx);
            float ds = e;
#pragma unroll
            for (int off = 16; off >= 1; off >>= 1) ds += __shfl_xor(ds, off);
            sP[row * 40 + s] = (short)bf1(e * __builtin_amdgcn_rcpf(ds));
        }
    }
    __syncthreads();

    // ---- PV: o[r][n] = sum_s attn[r][s] V[s][n] ----
    {
        short* ot = (short*)uni;  // [64][40] bf16, o^T[n][r] (sS dead)
        const int rt = w & 1, ntb = (w >> 1) * 2;
        short8 pa = *(const short8*)&sP[(rt * 16 + m) * 40 + q * 8];
#pragma unroll
        for (int ni = 0; ni < 2; ++ni) {
            const int nt = ntb + ni;
            short8 vb = *(const short8*)&sVt[(nt * 16 + m) * 40 + q * 8];
            f32x4 c = {0.f, 0.f, 0.f, 0.f};
            c = __builtin_amdgcn_mfma_f32_16x16x32_bf16(pa, vb, c, 0, 0, 0);
            uint2 p2 = {pack2bf(c[0], c[1]), pack2bf(c[2], c[3])};
            *(uint2*)&ot[(nt * 16 + m) * 40 + (rt * 16 + q * 4)] = p2;
        }
    }
    __syncthreads();

    // ---- Rh[h][n] = tanh(Ao[h]·o[:,n]); R[b][h*64+n] = Rh^2 ----
    {
        const short* ot = (const short*)uni;
        short8 aa = *(const short8*)&Abf[6144 + m * 32 + q * 8];
        short8 bb = *(const short8*)&ot[(w * 16 + m) * 40 + q * 8];
        f32x4 c = {0.f, 0.f, 0.f, 0.f};
        c = __builtin_amdgcn_mfma_f32_16x16x32_bf16(aa, bb, c, 0, 0, 0);
        float* Rb = R + (size_t)b * 1024;
#pragma unroll
        for (int j = 0; j < 4; ++j) {
            float rh = fast_tanh(c[j]);
            Rb[(q * 4 + j) * 64 + w * 16 + m] = rh * rh;  // h = q*4+j, n = w*16+m
        }
    }
}

// ===== Phase 2: coalesced Rsym + Laplacian.
// out[row][col] = -(Rupper[row][col]) off-diag; out[row][row] = full rowsum.
// Rupper[row][col] = R[e][i][j*16+8hr+4hc+2pr+pc] + R[e][j][i*16+8hc+4hr+2pc+pr].
// Block = 4 rows (one per wave); lane j owns the 4 (hc,pc) cells of column group j.
__global__ __launch_bounds__(256)
void att_k2(const float* __restrict__ R, float* __restrict__ out) {
    const int e   = blockIdx.x >> 6;
    const int rg  = blockIdx.x & 63;
    const int w   = threadIdx.x >> 6;
    const int j   = threadIdx.x & 63;
    const int row = rg * 4 + w;
    const int hr = row >> 7, i = (row >> 1) & 63, pr = row & 1;

    const float* Re = R + (size_t)e * 65536;
    float* Oe       = out + (size_t)e * 65536;

    // t1: one 64B line R[i][j*16 ..]
    const float* t1p = Re + i * 1024 + j * 16 + 8 * hr + 2 * pr;
    float2 t1a = *(const float2*)t1p;        // (hc=0, pc=0/1)
    float2 t1b = *(const float2*)(t1p + 4);  // (hc=1, pc=0/1)
    // t2: 4 dwords from line R[j][i*16 ..]
    const float* t2p = Re + j * 1024 + i * 16 + 4 * hr + pr;
    float c00 = t1a.x + t2p[0];
    float c01 = t1a.y + t2p[2];
    float c10 = t1b.x + t2p[8];
    float c11 = t1b.y + t2p[10];

    float sum = c00 + c01 + c10 + c11;
#pragma unroll
    for (int off = 32; off >= 1; off >>= 1) sum += __shfl_xor(sum, off);  // full rowsum

    // diagonal lands at lane j==i, cell (hc==hr, pc==pr)
    float v00 = -c00, v01 = -c01, v10 = -c10, v11 = -c11;
    if (j == i) {
        if (hr == 0) { if (pr == 0) v00 = sum; else v01 = sum; }
        else         { if (pr == 0) v10 = sum; else v11 = sum; }
    }
    float2 z0 = {v00, v01}, z1 = {v10, v11};
    *(float2*)&Oe[row * 256 + 2 * j]       = z0;
    *(float2*)&Oe[row * 256 + 128 + 2 * j] = z1;
}

// ===== Fallback path (tiny ws): VALU kernel w/ atomic scatter + Laplacian =====
__global__ __launch_bounds__(256, 4)
void att_k1_atomic(const float* __restrict__ x, const float* __restrict__ L,
                   const float* __restrict__ Aq, const float* __restrict__ Ak,
                   const float* __restrict__ Av, const float* __restrict__ Ao,
                   float* __restrict__ out) {
    const int b    = blockIdx.x;
    const int t    = threadIdx.x;
    const int lane = t & 63;
    const int w    = t >> 6;
    const int wu   = __builtin_amdgcn_readfirstlane(w);

    __shared__ float sQ[32][68];
    __shared__ float sK[32][68];
    __shared__ float sV[32][68];
    __shared__ float sNum;

    const float* xb = x + (size_t)b * 4096;
    if (t < 64) {
        float lv = L[(size_t)b * 64 + t];
        unsigned long long mk = __ballot(lv >= 1.0f);
        if (t == 0) sNum = (float)__popcll(mk) + 1.0f;
    }
    float acc[3][8];
#pragma unroll
    for (int mm = 0; mm < 3; ++mm)
#pragma unroll
        for (int k = 0; k < 8; ++k) acc[mm][k] = 0.f;
    const float* Am[3] = {Aq, Ak, Av};
#pragma unroll
    for (int hf = 0; hf < 2; ++hf) {
        float xv[32];
#pragma unroll
        for (int d = 0; d < 32; ++d) xv[d] = xb[(hf * 32 + d) * 64 + lane];
#pragma unroll
        for (int mm = 0; mm < 3; ++mm)
#pragma unroll
            for (int k = 0; k < 8; ++k) {
                const float* Ar = Am[mm] + (wu + 4 * k) * 64 + hf * 32;
                float a = acc[mm][k];
#pragma unroll
                for (int d = 0; d < 32; ++d) a = fmaf(Ar[d], xv[d], a);
                acc[mm][k] = a;
            }
    }
    float(*const sMat[3])[68] = {sQ, sK, sV};
#pragma unroll
    for (int mm = 0; mm < 3; ++mm)
#pragma unroll
        for (int k = 0; k < 8; ++k)
            sMat[mm][wu + 4 * k][lane] = fast_tanh(acc[mm][k]);
    __syncthreads();

    const int s = lane & 31, half = lane >> 5;
    const float inv = rsqrtf(sNum);
    float kreg[32];
#pragma unroll
    for (int c = 0; c < 8; ++c) {
        float4 kv = *(const float4*)&sK[s][half * 32 + 4 * c];
        kreg[4 * c] = kv.x; kreg[4 * c + 1] = kv.y;
        kreg[4 * c + 2] = kv.z; kreg[4 * c + 3] = kv.w;
    }
    float sc8[8];
#pragma unroll
    for (int kk = 0; kk < 8; ++kk) {
        float sc = 0.f;
#pragma unroll
        for (int c = 0; c < 8; ++c) {
            float4 qv = *(const float4*)&sQ[wu + 4 * kk][half * 32 + 4 * c];
            sc = fmaf(qv.x, kreg[4 * c], sc);
            sc = fmaf(qv.y, kreg[4 * c + 1], sc);
            sc = fmaf(qv.z, kreg[4 * c + 2], sc);
            sc = fmaf(qv.w, kreg[4 * c + 3], sc);
        }
        sc += __shfl_xor(sc, 32);
        sc8[kk] = sc * inv;
    }
    float pown[4];
#pragma unroll
    for (int qq = 0; qq < 4; ++qq) pown[qq] = half ? sc8[2 * qq + 1] : sc8[2 * qq];
#pragma unroll
    for (int qq = 0; qq < 4; ++qq) {
        float mx = pown[qq];
#pragma unroll
        for (int off = 16; off >= 1; off >>= 1) mx = fmaxf(mx, __shfl_xor(mx, off));
        float e = __expf(pown[qq] - mx);
        float ds = e;
#pragma unroll
        for (int off = 16; off >= 1; off >>= 1) ds += __shfl_xor(ds, off);
        pown[qq] = e * __builtin_amdgcn_rcpf(ds);
    }
    __syncthreads();
#pragma unroll
    for (int qq = 0; qq < 4; ++qq) sQ[wu + 8 * qq + 4 * half][s] = pown[qq];
    __syncthreads();
    float oacc[8];
#pragma unroll
    for (int k = 0; k < 8; ++k) oacc[k] = 0.f;
#pragma unroll
    for (int sb = 0; sb < 8; ++sb) {
        float4 arow[8];
#pragma unroll
        for (int kk = 0; kk < 8; ++kk) arow[kk] = *(const float4*)&sQ[wu + 4 * kk][4 * sb];
#pragma unroll
        for (int ds2 = 0; ds2 < 4; ++ds2) {
            float vv = sV[4 * sb + ds2][lane];
#pragma unroll
            for (int kk = 0; kk < 8; ++kk) {
                float a = (ds2 == 0) ? arow[kk].x : (ds2 == 1) ? arow[kk].y
                        : (ds2 == 2) ? arow[kk].z : arow[kk].w;
                oacc[kk] = fmaf(a, vv, oacc[kk]);
            }
        }
    }
#pragma unroll
    for (int k = 0; k < 8; ++k) sK[wu + 4 * k][lane] = oacc[k];
    __syncthreads();
    float col[32];
#pragma unroll
    for (int r = 0; r < 32; ++r) col[r] = sK[r][lane];
#pragma unroll
    for (int k = 0; k < 4; ++k) {
        const int h = wu + 4 * k;
        const float* AoR = Ao + h * 32;
        float a2 = 0.f;
#pragma unroll
        for (int r = 0; r < 32; ++r) a2 = fmaf(AoR[r], col[r], a2);
        float rh = fast_tanh(a2);
        float val = rh * rh;
        const int e = b >> 6, i = b & 63;
        const int c = h * 64 + lane;
        const int jj = c >> 4, k4 = c & 15;
        const int hr = (k4 >> 3) & 1, hc = (k4 >> 2) & 1;
        const int pr = (k4 >> 1) & 1, pc = k4 & 1;
        const int row = hr * 128 + 2 * i + pr;
        const int colo = hc * 128 + 2 * jj + pc;
        float* oe = out + (size_t)e * 65536;
        atomicAdd(&oe[row * 256 + colo], val);
        atomicAdd(&oe[colo * 256 + row], val);
    }
}

__global__ __launch_bounds__(256)
void att_k3(float* __restrict__ out) {
    const size_t rowbase = (size_t)blockIdx.x * 256;
    const int t = threadIdx.x;
    float v = out[rowbase + t];
    float sum = v;
#pragma unroll
    for (int off = 32; off >= 1; off >>= 1) sum += __shfl_xor(sum, off);
    __shared__ float red[4];
    if ((t & 63) == 0) red[t >> 6] = sum;
    __syncthreads();
    float tot = red[0] + red[1] + red[2] + red[3];
    const int row = blockIdx.x & 255;
    out[rowbase + t] = (t == row) ? tot : -v;
}

extern "C" void kernel_launch(void* const* d_in, const int* in_sizes, int n_in,
                              void* d_out, int out_size, void* d_ws, size_t ws_size,
                              hipStream_t stream) {
    const float* x  = (const float*)d_in[0];
    const float* L  = (const float*)d_in[1];
    const float* Aq = (const float*)d_in[2];
    const float* Ak = (const float*)d_in[3];
    const float* Av = (const float*)d_in[4];
    const float* Ao = (const float*)d_in[5];
    float* out = (float*)d_out;

    const size_t rbytes = (size_t)Bn * 1024 * sizeof(float);
    const size_t need   = rbytes + 6656 * sizeof(short);
    if (ws_size >= need) {
        float* R   = (float*)d_ws;
        short* Abf = (short*)((char*)d_ws + rbytes);
        att_prep<<<1, 256, 0, stream>>>(Aq, Ak, Av, Ao, Abf);
        att_m1<<<Bn, 256, 0, stream>>>(x, L, Abf, R);
        att_k2<<<Ee * 64, 256, 0, stream>>>(R, out);
    } else {
        (void)hipMemsetAsync(d_out, 0, (size_t)out_size * sizeof(float), stream);
        att_k1_atomic<<<Bn, 256, 0, stream>>>(x, L, Aq, Ak, Av, Ao, out);
        att_k3<<<Ee * 256, 256, 0, stream>>>(out);
    }
}

// Round 7
// 89.924 us; speedup vs baseline: 2.7274x; 1.0050x over previous
//
#include <hip/hip_runtime.h>
#include <math.h>

#define Bn 8192
#define Ee 128

typedef __attribute__((ext_vector_type(8))) short short8;   // 8 bf16 (4 VGPR) MFMA A/B frag
typedef __attribute__((ext_vector_type(4))) float f32x4;    // MFMA C/D frag

// ds_swizzle XOR-mode lane exchange: pat = (xor_mask<<10) | 0x1F, compile-time.
#define SWZ(v, pat) __builtin_bit_cast(float, __builtin_amdgcn_ds_swizzle(__builtin_bit_cast(int, v), pat))

// tanh(x) = 1 - 2/(1+e^{2x}); v_exp + v_rcp, bf16-accuracy, no clamp needed.
__device__ __forceinline__ float fast_tanh(float x) {
    float e = __expf(2.f * x);
    return fmaf(-2.f, __builtin_amdgcn_rcpf(1.f + e), 1.f);
}

__device__ __forceinline__ unsigned int bf1(float a) {
    return (__builtin_bit_cast(unsigned int, a) + 0x8000u) >> 16;
}
__device__ __forceinline__ unsigned int pack2bf(float a, float b) {
    unsigned int ua = (__builtin_bit_cast(unsigned int, a) + 0x8000u) >> 16;
    unsigned int ub = (__builtin_bit_cast(unsigned int, b) + 0x8000u) & 0xffff0000u;
    return ua | ub;
}

// ---- prep: one-shot f32->bf16 conversion of Aq/Ak/Av (3x[32][64]) + Ao ([16][32])
__global__ __launch_bounds__(256)
void att_prep(const float* __restrict__ Aq, const float* __restrict__ Ak,
              const float* __restrict__ Av, const float* __restrict__ Ao,
              short* __restrict__ Abf) {
    const int t = threadIdx.x;
    const float* Am[3] = {Aq, Ak, Av};
#pragma unroll
    for (int mat = 0; mat < 3; ++mat) {
        float4 v0 = *(const float4*)(Am[mat] + t * 8);
        float4 v1 = *(const float4*)(Am[mat] + t * 8 + 4);
        uint4 pk = {pack2bf(v0.x, v0.y), pack2bf(v0.z, v0.w),
                    pack2bf(v1.x, v1.y), pack2bf(v1.z, v1.w)};
        *(uint4*)&Abf[mat * 2048 + t * 8] = pk;
    }
    if (t < 64) {
        float4 v0 = *(const float4*)(Ao + t * 8);
        float4 v1 = *(const float4*)(Ao + t * 8 + 4);
        uint4 pk = {pack2bf(v0.x, v0.y), pack2bf(v0.z, v0.w),
                    pack2bf(v1.x, v1.y), pack2bf(v1.z, v1.w)};
        *(uint4*)&Abf[6144 + t * 8] = pk;
    }
}

// ============================ MFMA main kernel ============================
// One block per batch element b. 4 waves, 3 barriers. All GEMMs 16x16x32 bf16.
// A-frag: row=lane&15, k=(lane>>4)*8+j. B-frag: col=lane&15, k same.
// C/D: col=lane&15, row=(lane>>4)*4+reg.
__global__ __launch_bounds__(256, 6)
void att_m1(const float* __restrict__ x, const float* __restrict__ L,
            const short* __restrict__ Abf, float* __restrict__ R) {
    const int b    = blockIdx.x;
    const int t    = threadIdx.x;
    const int lane = t & 63;
    const int w    = t >> 6;        // wave 0..3
    const int q    = lane >> 4;     // quarter 0..3
    const int m    = lane & 15;

    __shared__ __align__(16) short sQ[32 * 72];      // Q bf16 [r][n], 144B rows
    __shared__ __align__(16) short sK[32 * 72];      // K bf16 [s][n]
    __shared__ __align__(16) short sVt[64 * 40];     // V^T bf16 [n][s], 80B rows
    __shared__ __align__(16) short sP[32 * 40];      // attn bf16 [r][s]
    __shared__ __align__(16) float uni[1320];        // union: sS f32[32][33] | ot bf16[64][40]
    __shared__ float sNum;

    // ---- x column loads (A-frags for QKV): lane holds x[kc*32+q*8+j][w*16+m] ----
    float xf[16];
    {
        const float* p0 = x + (size_t)b * 4096 + (q * 8) * 64 + (w * 16 + m);
#pragma unroll
        for (int j = 0; j < 8; ++j) xf[j] = p0[j * 64];
        const float* p1 = p0 + 32 * 64;
#pragma unroll
        for (int j = 0; j < 8; ++j) xf[8 + j] = p1[j * 64];
    }

    // ---- numN = count(L[b,0,:] >= 1) + 1 ----
    if (t < 64) {
        float lv = L[(size_t)b * 64 + t];
        unsigned long long mk = __ballot(lv >= 1.0f);
        if (t == 0) sNum = (float)__popcll(mk) + 1.0f;
    }

    // ---- QKV (transposed GEMM): D[n][r] = sum_d x[d][n] * Am[r][d] ----
    short8 afr[2];
    {
        uint4 pk0 = {pack2bf(xf[0], xf[1]), pack2bf(xf[2], xf[3]),
                     pack2bf(xf[4], xf[5]), pack2bf(xf[6], xf[7])};
        uint4 pk1 = {pack2bf(xf[8], xf[9]), pack2bf(xf[10], xf[11]),
                     pack2bf(xf[12], xf[13]), pack2bf(xf[14], xf[15])};
        afr[0] = __builtin_bit_cast(short8, pk0);
        afr[1] = __builtin_bit_cast(short8, pk1);
    }
#pragma unroll
    for (int mat = 0; mat < 3; ++mat) {
#pragma unroll
        for (int rt = 0; rt < 2; ++rt) {
            const short* Ab = Abf + mat * 2048 + (rt * 16 + m) * 64 + q * 8;
            short8 bfr0 = *(const short8*)Ab;          // d = q*8..+8
            short8 bfr1 = *(const short8*)(Ab + 32);   // d = 32+q*8..+8
            f32x4 c = {0.f, 0.f, 0.f, 0.f};
            c = __builtin_amdgcn_mfma_f32_16x16x32_bf16(afr[0], bfr0, c, 0, 0, 0);
            c = __builtin_amdgcn_mfma_f32_16x16x32_bf16(afr[1], bfr1, c, 0, 0, 0);
            float tv[4];
#pragma unroll
            for (int j = 0; j < 4; ++j) tv[j] = fast_tanh(c[j]);
            if (mat < 2) {
                // C^T write -> row-major mat[r][n]: r = rt*16+m, n0 = w*16+q*4
                uint2 p2 = {pack2bf(tv[0], tv[1]), pack2bf(tv[2], tv[3])};
                short* dst = (mat == 0) ? sQ : sK;
                *(uint2*)&dst[(rt * 16 + m) * 72 + (w * 16 + q * 4)] = p2;
            } else {
                // V: straight write V^T[n][s]: n = w*16+q*4+j, s = rt*16+m
#pragma unroll
                for (int j = 0; j < 4; ++j)
                    sVt[(w * 16 + q * 4 + j) * 40 + (rt * 16 + m)] = (short)bf1(tv[j]);
            }
        }
    }
    __syncthreads();   // (1) Q/K/V staged

    // ---- scores + exp: sS[r][s] = exp((Q[r]·K[s]) * rsqrt(numN)) ----
    // Safe without max-subtraction: |score| <= 64 -> exp in [1.6e-28, 6.3e27].
    const int wr = w & 1, ws = w >> 1;
    {
        float* sS = uni;  // [32][33] f32
        short8 qa0 = *(const short8*)&sQ[(wr * 16 + m) * 72 + q * 8];
        short8 qa1 = *(const short8*)&sQ[(wr * 16 + m) * 72 + 32 + q * 8];
        short8 kb0 = *(const short8*)&sK[(ws * 16 + m) * 72 + q * 8];
        short8 kb1 = *(const short8*)&sK[(ws * 16 + m) * 72 + 32 + q * 8];
        f32x4 c = {0.f, 0.f, 0.f, 0.f};
        c = __builtin_amdgcn_mfma_f32_16x16x32_bf16(qa0, kb0, c, 0, 0, 0);
        c = __builtin_amdgcn_mfma_f32_16x16x32_bf16(qa1, kb1, c, 0, 0, 0);
        float inv = rsqrtf(sNum);
#pragma unroll
        for (int j = 0; j < 4; ++j)
            sS[(wr * 16 + q * 4 + j) * 33 + ws * 16 + m] = __expf(c[j] * inv);
    }
    __syncthreads();   // (2) exp'd scores staged

    // ---- normalize: p / rowsum via ds_swizzle XOR reduction (no max pass) ----
    {
        const float* sS = uni;
        const int s = lane & 31, half = lane >> 5;
#pragma unroll
        for (int qq = 0; qq < 4; ++qq) {
            const int row = w + 8 * qq + 4 * half;
            float p = sS[row * 33 + s];
            float ds = p;
            ds += SWZ(ds, 0x041F);
            ds += SWZ(ds, 0x081F);
            ds += SWZ(ds, 0x101F);
            ds += SWZ(ds, 0x201F);
            ds += SWZ(ds, 0x401F);
            sP[row * 40 + s] = (short)bf1(p * __builtin_amdgcn_rcpf(ds));
        }
    }
    __syncthreads();   // (3) attn staged

    // ---- PV: wave w owns n-tile nt=w, computes both rt halves ----
    {
        short* ot = (short*)uni;  // [64][40] bf16, o^T[n][r] (sS dead)
        short8 vb = *(const short8*)&sVt[(w * 16 + m) * 40 + q * 8];
#pragma unroll
        for (int rt = 0; rt < 2; ++rt) {
            short8 pa = *(const short8*)&sP[(rt * 16 + m) * 40 + q * 8];
            f32x4 c = {0.f, 0.f, 0.f, 0.f};
            c = __builtin_amdgcn_mfma_f32_16x16x32_bf16(pa, vb, c, 0, 0, 0);
            // o[r=rt*16+q*4+j][n=w*16+m] -> ot[n][r]
            uint2 p2 = {pack2bf(c[0], c[1]), pack2bf(c[2], c[3])};
            *(uint2*)&ot[(w * 16 + m) * 40 + (rt * 16 + q * 4)] = p2;
        }
    }
    // no barrier: Rh reads only ot rows n = w*16+m written by this wave (lgkmcnt-ordered)

    // ---- Rh[h][n] = tanh(Ao[h]·o[:,n]); R[b][h*64+n] = Rh^2 ----
    {
        const short* ot = (const short*)uni;
        short8 aa = *(const short8*)&Abf[6144 + m * 32 + q * 8];
        short8 bb = *(const short8*)&ot[(w * 16 + m) * 40 + q * 8];
        f32x4 c = {0.f, 0.f, 0.f, 0.f};
        c = __builtin_amdgcn_mfma_f32_16x16x32_bf16(aa, bb, c, 0, 0, 0);
        float* Rb = R + (size_t)b * 1024;
#pragma unroll
        for (int j = 0; j < 4; ++j) {
            float rh = fast_tanh(c[j]);
            Rb[(q * 4 + j) * 64 + w * 16 + m] = rh * rh;  // h = q*4+j, n = w*16+m
        }
    }
}

// ===== Phase 2: coalesced Rsym + Laplacian =====
__global__ __launch_bounds__(256)
void att_k2(const float* __restrict__ R, float* __restrict__ out) {
    const int e   = blockIdx.x >> 6;
    const int rg  = blockIdx.x & 63;
    const int w   = threadIdx.x >> 6;
    const int j   = threadIdx.x & 63;
    const int row = rg * 4 + w;
    const int hr = row >> 7, i = (row >> 1) & 63, pr = row & 1;

    const float* Re = R + (size_t)e * 65536;
    float* Oe       = out + (size_t)e * 65536;

    const float* t1p = Re + i * 1024 + j * 16 + 8 * hr + 2 * pr;
    float2 t1a = *(const float2*)t1p;        // (hc=0, pc=0/1)
    float2 t1b = *(const float2*)(t1p + 4);  // (hc=1, pc=0/1)
    const float* t2p = Re + j * 1024 + i * 16 + 4 * hr + pr;
    float c00 = t1a.x + t2p[0];
    float c01 = t1a.y + t2p[2];
    float c10 = t1b.x + t2p[8];
    float c11 = t1b.y + t2p[10];

    float sum = c00 + c01 + c10 + c11;
#pragma unroll
    for (int off = 32; off >= 1; off >>= 1) sum += __shfl_xor(sum, off);

    float v00 = -c00, v01 = -c01, v10 = -c10, v11 = -c11;
    if (j == i) {
        if (hr == 0) { if (pr == 0) v00 = sum; else v01 = sum; }
        else         { if (pr == 0) v10 = sum; else v11 = sum; }
    }
    float2 z0 = {v00, v01}, z1 = {v10, v11};
    *(float2*)&Oe[row * 256 + 2 * j]       = z0;
    *(float2*)&Oe[row * 256 + 128 + 2 * j] = z1;
}

// ===== Fallback path (tiny ws): VALU kernel w/ atomic scatter + Laplacian =====
__global__ __launch_bounds__(256, 4)
void att_k1_atomic(const float* __restrict__ x, const float* __restrict__ L,
                   const float* __restrict__ Aq, const float* __restrict__ Ak,
                   const float* __restrict__ Av, const float* __restrict__ Ao,
                   float* __restrict__ out) {
    const int b    = blockIdx.x;
    const int t    = threadIdx.x;
    const int lane = t & 63;
    const int w    = t >> 6;
    const int wu   = __builtin_amdgcn_readfirstlane(w);

    __shared__ float sQ[32][68];
    __shared__ float sK[32][68];
    __shared__ float sV[32][68];
    __shared__ float sNum;

    const float* xb = x + (size_t)b * 4096;
    if (t < 64) {
        float lv = L[(size_t)b * 64 + t];
        unsigned long long mk = __ballot(lv >= 1.0f);
        if (t == 0) sNum = (float)__popcll(mk) + 1.0f;
    }
    float acc[3][8];
#pragma unroll
    for (int mm = 0; mm < 3; ++mm)
#pragma unroll
        for (int k = 0; k < 8; ++k) acc[mm][k] = 0.f;
    const float* Am[3] = {Aq, Ak, Av};
#pragma unroll
    for (int hf = 0; hf < 2; ++hf) {
        float xv[32];
#pragma unroll
        for (int d = 0; d < 32; ++d) xv[d] = xb[(hf * 32 + d) * 64 + lane];
#pragma unroll
        for (int mm = 0; mm < 3; ++mm)
#pragma unroll
            for (int k = 0; k < 8; ++k) {
                const float* Ar = Am[mm] + (wu + 4 * k) * 64 + hf * 32;
                float a = acc[mm][k];
#pragma unroll
                for (int d = 0; d < 32; ++d) a = fmaf(Ar[d], xv[d], a);
                acc[mm][k] = a;
            }
    }
    float(*const sMat[3])[68] = {sQ, sK, sV};
#pragma unroll
    for (int mm = 0; mm < 3; ++mm)
#pragma unroll
        for (int k = 0; k < 8; ++k)
            sMat[mm][wu + 4 * k][lane] = fast_tanh(acc[mm][k]);
    __syncthreads();

    const int s = lane & 31, half = lane >> 5;
    const float inv = rsqrtf(sNum);
    float kreg[32];
#pragma unroll
    for (int c = 0; c < 8; ++c) {
        float4 kv = *(const float4*)&sK[s][half * 32 + 4 * c];
        kreg[4 * c] = kv.x; kreg[4 * c + 1] = kv.y;
        kreg[4 * c + 2] = kv.z; kreg[4 * c + 3] = kv.w;
    }
    float sc8[8];
#pragma unroll
    for (int kk = 0; kk < 8; ++kk) {
        float sc = 0.f;
#pragma unroll
        for (int c = 0; c < 8; ++c) {
            float4 qv = *(const float4*)&sQ[wu + 4 * kk][half * 32 + 4 * c];
            sc = fmaf(qv.x, kreg[4 * c], sc);
            sc = fmaf(qv.y, kreg[4 * c + 1], sc);
            sc = fmaf(qv.z, kreg[4 * c + 2], sc);
            sc = fmaf(qv.w, kreg[4 * c + 3], sc);
        }
        sc += __shfl_xor(sc, 32);
        sc8[kk] = sc * inv;
    }
    float pown[4];
#pragma unroll
    for (int qq = 0; qq < 4; ++qq) pown[qq] = half ? sc8[2 * qq + 1] : sc8[2 * qq];
#pragma unroll
    for (int qq = 0; qq < 4; ++qq) {
        float e = __expf(pown[qq]);
        float ds = e;
#pragma unroll
        for (int off = 16; off >= 1; off >>= 1) ds += __shfl_xor(ds, off);
        pown[qq] = e * __builtin_amdgcn_rcpf(ds);
    }
    __syncthreads();
#pragma unroll
    for (int qq = 0; qq < 4; ++qq) sQ[wu + 8 * qq + 4 * half][s] = pown[qq];
    __syncthreads();
    float oacc[8];
#pragma unroll
    for (int k = 0; k < 8; ++k) oacc[k] = 0.f;
#pragma unroll
    for (int sb = 0; sb < 8; ++sb) {
        float4 arow[8];
#pragma unroll
        for (int kk = 0; kk < 8; ++kk) arow[kk] = *(const float4*)&sQ[wu + 4 * kk][4 * sb];
#pragma unroll
        for (int ds2 = 0; ds2 < 4; ++ds2) {
            float vv = sV[4 * sb + ds2][lane];
#pragma unroll
            for (int kk = 0; kk < 8; ++kk) {
                float a = (ds2 == 0) ? arow[kk].x : (ds2 == 1) ? arow[kk].y
                        : (ds2 == 2) ? arow[kk].z : arow[kk].w;
                oacc[kk] = fmaf(a, vv, oacc[kk]);
            }
        }
    }
#pragma unroll
    for (int k = 0; k < 8; ++k) sK[wu + 4 * k][lane] = oacc[k];
    __syncthreads();
    float col[32];
#pragma unroll
    for (int r = 0; r < 32; ++r) col[r] = sK[r][lane];
#pragma unroll
    for (int k = 0; k < 4; ++k) {
        const int h = wu + 4 * k;
        const float* AoR = Ao + h * 32;
        float a2 = 0.f;
#pragma unroll
        for (int r = 0; r < 32; ++r) a2 = fmaf(AoR[r], col[r], a2);
        float rh = fast_tanh(a2);
        float val = rh * rh;
        const int e = b >> 6, i = b & 63;
        const int c = h * 64 + lane;
        const int jj = c >> 4, k4 = c & 15;
        const int hr = (k4 >> 3) & 1, hc = (k4 >> 2) & 1;
        const int pr = (k4 >> 1) & 1, pc = k4 & 1;
        const int row = hr * 128 + 2 * i + pr;
        const int colo = hc * 128 + 2 * jj + pc;
        float* oe = out + (size_t)e * 65536;
        atomicAdd(&oe[row * 256 + colo], val);
        atomicAdd(&oe[colo * 256 + row], val);
    }
}

__global__ __launch_bounds__(256)
void att_k3(float* __restrict__ out) {
    const size_t rowbase = (size_t)blockIdx.x * 256;
    const int t = threadIdx.x;
    float v = out[rowbase + t];
    float sum = v;
#pragma unroll
    for (int off = 32; off >= 1; off >>= 1) sum += __shfl_xor(sum, off);
    __shared__ float red[4];
    if ((t & 63) == 0) red[t >> 6] = sum;
    __syncthreads();
    float tot = red[0] + red[1] + red[2] + red[3];
    const int row = blockIdx.x & 255;
    out[rowbase + t] = (t == row) ? tot : -v;
}

extern "C" void kernel_launch(void* const* d_in, const int* in_sizes, int n_in,
                              void* d_out, int out_size, void* d_ws, size_t ws_size,
                              hipStream_t stream) {
    const float* x  = (const float*)d_in[0];
    const float* L  = (const float*)d_in[1];
    const float* Aq = (const float*)d_in[2];
    const float* Ak = (const float*)d_in[3];
    const float* Av = (const float*)d_in[4];
    const float* Ao = (const float*)d_in[5];
    float* out = (float*)d_out;

    const size_t rbytes = (size_t)Bn * 1024 * sizeof(float);
    const size_t need   = rbytes + 6656 * sizeof(short);
    if (ws_size >= need) {
        float* R   = (float*)d_ws;
        short* Abf = (short*)((char*)d_ws + rbytes);
        att_prep<<<1, 256, 0, stream>>>(Aq, Ak, Av, Ao, Abf);
        att_m1<<<Bn, 256, 0, stream>>>(x, L, Abf, R);
        att_k2<<<Ee * 64, 256, 0, stream>>>(R, out);
    } else {
        (void)hipMemsetAsync(d_out, 0, (size_t)out_size * sizeof(float), stream);
        att_k1_atomic<<<Bn, 256, 0, stream>>>(x, L, Aq, Ak, Av, Ao, out);
        att_k3<<<Ee * 256, 256, 0, stream>>>(out);
    }
}